// Round 1
// baseline (2256.326 us; speedup 1.0000x reference)
//
#include <hip/hip_runtime.h>
#include <math.h>

#define NEG_SLOPE 0.2f

// ---------------- CSR build ----------------
__global__ void k_count(const int* __restrict__ dst, int E, int N, int* __restrict__ cnt){
  int i = blockIdx.x*blockDim.x + threadIdx.x;
  if (i < E) atomicAdd(&cnt[dst[i]], 1);
  else if (i < E + N) atomicAdd(&cnt[i - E], 1);   // self loops
}

__global__ void k_scan_block(const int* __restrict__ cnt, int* __restrict__ ex,
                             int* __restrict__ bsum, int N){
  __shared__ int tmp[256];
  int t = threadIdx.x;
  int i = blockIdx.x*256 + t;
  int v = (i < N) ? cnt[i] : 0;
  tmp[t] = v; __syncthreads();
  for (int off = 1; off < 256; off <<= 1){
    int u = (t >= off) ? tmp[t-off] : 0;
    __syncthreads();
    tmp[t] += u;
    __syncthreads();
  }
  if (i < N) ex[i] = tmp[t] - v;          // exclusive within block
  if (t == 255) bsum[blockIdx.x] = tmp[255];
}

__global__ void k_scan_tops(int* __restrict__ bsum, int nb){
  __shared__ int tmp[256];
  int t = threadIdx.x;
  int v = (t < nb) ? bsum[t] : 0;
  tmp[t] = v; __syncthreads();
  for (int off = 1; off < 256; off <<= 1){
    int u = (t >= off) ? tmp[t-off] : 0;
    __syncthreads();
    tmp[t] += u;
    __syncthreads();
  }
  if (t < nb) bsum[t] = tmp[t] - v;       // exclusive block offsets
}

__global__ void k_scan_add(int* __restrict__ row_start, const int* __restrict__ bsum,
                           int N, int total){
  int i = blockIdx.x*256 + threadIdx.x;
  if (i < N) row_start[i] += bsum[blockIdx.x];
  if (i == 0) row_start[N] = total;
}

__global__ void k_scatter(const int* __restrict__ src, const int* __restrict__ dst,
                          int E, int N, const int* __restrict__ row_start,
                          int* __restrict__ cursor, int* __restrict__ edge_src){
  int i = blockIdx.x*blockDim.x + threadIdx.x;
  if (i < E){
    int d = dst[i];
    int p = atomicAdd(&cursor[d], 1);
    edge_src[row_start[d] + p] = src[i];
  } else if (i < E + N){
    int n = i - E;
    int p = atomicAdd(&cursor[n], 1);
    edge_src[row_start[n] + p] = n;
  }
}

// ---------------- fp32 GEMM: C = A[M,K] @ W[K,Nw] + b ----------------
__global__ __launch_bounds__(256) void k_gemm_bias(const float* __restrict__ A,
                                                   const float* __restrict__ W,
                                                   const float* __restrict__ b,
                                                   float* __restrict__ Cout,
                                                   int M, int K, int Nw){
  __shared__ float sA[64][65];
  __shared__ float sW[64][65];
  int t = threadIdx.x;
  int row0 = blockIdx.x * 64;
  int col0 = blockIdx.y * 64;
  int ty = t >> 4, tx = t & 15;
  float acc[4][4] = {};
  for (int kk = 0; kk < K; kk += 64){
    #pragma unroll
    for (int it = 0; it < 16; ++it){
      int idx = it*256 + t;
      int r = idx >> 6, c = idx & 63;
      int gr = row0 + r;
      sA[r][c] = (gr < M) ? A[(size_t)gr*K + kk + c] : 0.f;
      sW[r][c] = W[(size_t)(kk + r)*Nw + col0 + c];
    }
    __syncthreads();
    #pragma unroll
    for (int k = 0; k < 64; ++k){
      float a[4], w[4];
      #pragma unroll
      for (int i = 0; i < 4; ++i) a[i] = sA[ty + 16*i][k];
      #pragma unroll
      for (int j = 0; j < 4; ++j) w[j] = sW[k][tx + 16*j];
      #pragma unroll
      for (int i = 0; i < 4; ++i)
        #pragma unroll
        for (int j = 0; j < 4; ++j)
          acc[i][j] += a[i]*w[j];
    }
    __syncthreads();
  }
  #pragma unroll
  for (int i = 0; i < 4; ++i){
    int r = row0 + ty + 16*i;
    if (r < M){
      #pragma unroll
      for (int j = 0; j < 4; ++j){
        int c = col0 + tx + 16*j;
        Cout[(size_t)r*Nw + c] = acc[i][j] + b[c];
      }
    }
  }
}

// ---------------- GATv2 aggregation: one wave per dst node ----------------
// channel mapping: lane l, slot j -> global channel g = j*64 + l, head = g / C
template<int HC, int C>
__global__ __launch_bounds__(256) void k_gat_agg(const float* __restrict__ xl,
                                                 const float* __restrict__ xr,
                                                 const float* __restrict__ att,
                                                 const float* __restrict__ bias,
                                                 const int* __restrict__ row_start,
                                                 const int* __restrict__ edge_src,
                                                 float* __restrict__ out,
                                                 int N, int apply_elu){
  constexpr int VPL = HC/64;
  constexpr int H = HC/C;
  int wid = (int)(((size_t)blockIdx.x * blockDim.x + threadIdx.x) >> 6);
  int lane = threadIdx.x & 63;
  if (wid >= N) return;
  float attr[VPL], xrr[VPL];
  #pragma unroll
  for (int j = 0; j < VPL; ++j){
    attr[j] = att[j*64 + lane];
    xrr[j]  = xr[(size_t)wid*HC + j*64 + lane];
  }
  float m[H], s[H], acc[VPL];
  #pragma unroll
  for (int h = 0; h < H; ++h){ m[h] = -INFINITY; s[h] = 0.f; }
  #pragma unroll
  for (int j = 0; j < VPL; ++j) acc[j] = 0.f;

  int e0 = row_start[wid], e1 = row_start[wid+1];
  for (int e = e0; e < e1; ++e){
    int sn = edge_src[e];
    float xlv[VPL], tv[VPL];
    #pragma unroll
    for (int j = 0; j < VPL; ++j){
      float xv = xl[(size_t)sn*HC + j*64 + lane];
      xlv[j] = xv;
      float v = xv + xrr[j];
      v = (v > 0.f) ? v : NEG_SLOPE*v;
      tv[j] = v * attr[j];
    }
    // 64-lane butterfly sum (per slot j -> per-head partial)
    #pragma unroll
    for (int off = 32; off > 0; off >>= 1){
      #pragma unroll
      for (int j = 0; j < VPL; ++j) tv[j] += __shfl_xor(tv[j], off, 64);
    }
    float logit[H];
    #pragma unroll
    for (int h = 0; h < H; ++h) logit[h] = 0.f;
    #pragma unroll
    for (int j = 0; j < VPL; ++j) logit[(j*64)/C] += tv[j];

    float wo[H], p[H];
    #pragma unroll
    for (int h = 0; h < H; ++h){
      float nm = fmaxf(m[h], logit[h]);
      wo[h] = __expf(m[h] - nm);      // first edge: exp(-inf)=0
      p[h]  = __expf(logit[h] - nm);
      s[h]  = s[h]*wo[h] + p[h];
      m[h]  = nm;
    }
    #pragma unroll
    for (int j = 0; j < VPL; ++j){
      int h = (j*64)/C;
      acc[j] = acc[j]*wo[h] + p[h]*xlv[j];
    }
  }
  #pragma unroll
  for (int j = 0; j < VPL; ++j){
    int h = (j*64)/C;
    int g = j*64 + lane;
    float o = acc[j]/s[h] + bias[g];
    if (apply_elu) o = (o > 0.f) ? o : (__expf(o) - 1.f);
    out[(size_t)wid*HC + g] = o;
  }
}

// ---------------- global mean pool ----------------
__global__ void k_pool(const float* __restrict__ h, const int* __restrict__ batch,
                       float* __restrict__ pool, int* __restrict__ gcnt, int N){
  int wid = (int)(((size_t)blockIdx.x * blockDim.x + threadIdx.x) >> 6);
  int lane = threadIdx.x & 63;
  if (wid >= N) return;
  int g = batch[wid];
  #pragma unroll
  for (int j = 0; j < 2; ++j)
    atomicAdd(&pool[(size_t)g*128 + j*64 + lane], h[(size_t)wid*128 + j*64 + lane]);
  if (lane == 0) atomicAdd(&gcnt[g], 1);
}

__global__ void k_pool_div(const float* __restrict__ pool, const int* __restrict__ gcnt,
                           float* __restrict__ out, int total){
  int i = blockIdx.x*blockDim.x + threadIdx.x;
  if (i < total) out[i] = pool[i] / fmaxf((float)gcnt[i >> 7], 1.f);
}

extern "C" void kernel_launch(void* const* d_in, const int* in_sizes, int n_in,
                              void* d_out, int out_size, void* d_ws, size_t ws_size,
                              hipStream_t stream){
  const float* x    = (const float*)d_in[0];
  const int*   ei   = (const int*)  d_in[1];
  const int*   batch= (const int*)  d_in[2];
  const float* Wl1  = (const float*)d_in[3];
  const float* bl1  = (const float*)d_in[4];
  const float* Wr1  = (const float*)d_in[5];
  const float* br1  = (const float*)d_in[6];
  const float* att1 = (const float*)d_in[7];
  const float* b1   = (const float*)d_in[8];
  const float* Wl2  = (const float*)d_in[9];
  const float* bl2  = (const float*)d_in[10];
  const float* Wr2  = (const float*)d_in[11];
  const float* br2  = (const float*)d_in[12];
  const float* att2 = (const float*)d_in[13];
  const float* b2   = (const float*)d_in[14];
  const float* Wl3  = (const float*)d_in[15];
  const float* bl3  = (const float*)d_in[16];
  const float* Wr3  = (const float*)d_in[17];
  const float* br3  = (const float*)d_in[18];
  const float* att3 = (const float*)d_in[19];
  const float* b3   = (const float*)d_in[20];

  int N  = in_sizes[2];          // 50000
  int E  = in_sizes[1] / 2;      // 800000
  int NG = out_size / 128;       // 1000
  const int* esrc = ei;
  const int* edst = ei + E;

  size_t off = 0;
  char* base = (char*)d_ws;
  auto alloc = [&](size_t bytes)->void*{
    void* p = base + off;
    off += (bytes + 255) & ~(size_t)255;
    return p;
  };
  float* XL  = (float*)alloc((size_t)N*256*sizeof(float));
  float* XR  = (float*)alloc((size_t)N*256*sizeof(float));
  float* Hb  = (float*)alloc((size_t)N*256*sizeof(float));
  int* row_start = (int*)alloc(((size_t)N+1)*sizeof(int));
  int* edge_src  = (int*)alloc((size_t)(E+N)*sizeof(int));
  int* cnt       = (int*)alloc((size_t)N*sizeof(int));
  int* bsum      = (int*)alloc(256*sizeof(int));
  float* pool    = (float*)alloc((size_t)NG*128*sizeof(float));
  int* gcnt      = (int*)alloc((size_t)NG*sizeof(int));
  (void)ws_size; (void)n_in;

  int EN = E + N;
  int nb = (N + 255) / 256;

  // CSR build (per-call; inputs constant so result identical up to edge order)
  hipMemsetAsync(cnt, 0, (size_t)N*sizeof(int), stream);
  k_count<<<(EN+255)/256, 256, 0, stream>>>(edst, E, N, cnt);
  k_scan_block<<<nb, 256, 0, stream>>>(cnt, row_start, bsum, N);
  k_scan_tops<<<1, 256, 0, stream>>>(bsum, nb);
  k_scan_add<<<nb, 256, 0, stream>>>(row_start, bsum, N, EN);
  hipMemsetAsync(cnt, 0, (size_t)N*sizeof(int), stream);   // reuse as cursor
  k_scatter<<<(EN+255)/256, 256, 0, stream>>>(esrc, edst, E, N, row_start, cnt, edge_src);

  dim3 blk(256);
  dim3 gemm_g1((N+63)/64, 4);   // Nw = 256
  dim3 gemm_g3((N+63)/64, 2);   // Nw = 128
  int agg_blocks = (N + 3) / 4; // 4 waves/block

  // Layer 1: Din=64 -> 4x64
  k_gemm_bias<<<gemm_g1, blk, 0, stream>>>(x, Wl1, bl1, XL, N, 64, 256);
  k_gemm_bias<<<gemm_g1, blk, 0, stream>>>(x, Wr1, br1, XR, N, 64, 256);
  k_gat_agg<256,64><<<agg_blocks, blk, 0, stream>>>(XL, XR, att1, b1, row_start, edge_src, Hb, N, 1);

  // Layer 2: 256 -> 4x64
  k_gemm_bias<<<gemm_g1, blk, 0, stream>>>(Hb, Wl2, bl2, XL, N, 256, 256);
  k_gemm_bias<<<gemm_g1, blk, 0, stream>>>(Hb, Wr2, br2, XR, N, 256, 256);
  k_gat_agg<256,64><<<agg_blocks, blk, 0, stream>>>(XL, XR, att2, b2, row_start, edge_src, Hb, N, 1);

  // Layer 3: 256 -> 128, 1 head, no concat, no elu
  k_gemm_bias<<<gemm_g3, blk, 0, stream>>>(Hb, Wl3, bl3, XL, N, 256, 128);
  k_gemm_bias<<<gemm_g3, blk, 0, stream>>>(Hb, Wr3, br3, XR, N, 256, 128);
  k_gat_agg<128,128><<<agg_blocks, blk, 0, stream>>>(XL, XR, att3, b3, row_start, edge_src, Hb, N, 0);

  // Global mean pool
  hipMemsetAsync(pool, 0, (size_t)NG*128*sizeof(float), stream);
  hipMemsetAsync(gcnt, 0, (size_t)NG*sizeof(int), stream);
  k_pool<<<agg_blocks, blk, 0, stream>>>(Hb, batch, pool, gcnt, N);
  k_pool_div<<<(NG*128+255)/256, 256, 0, stream>>>(pool, gcnt, (float*)d_out, NG*128);
}

// Round 2
// 1107.359 us; speedup vs baseline: 2.0376x; 2.0376x over previous
//
#include <hip/hip_runtime.h>
#include <math.h>

#define NEG_SLOPE 0.2f

typedef _Float16 half8 __attribute__((ext_vector_type(8)));
typedef _Float16 half4 __attribute__((ext_vector_type(4)));
typedef float    f32x4 __attribute__((ext_vector_type(4)));
typedef float    fvec4 __attribute__((ext_vector_type(4)));

// ---------------- CSR build ----------------
__global__ void k_count(const int* __restrict__ dst, int E, int N, int* __restrict__ cnt){
  int i = blockIdx.x*blockDim.x + threadIdx.x;
  if (i < E) atomicAdd(&cnt[dst[i]], 1);
  else if (i < E + N) atomicAdd(&cnt[i - E], 1);   // self loops
}

__global__ void k_scan_block(const int* __restrict__ cnt, int* __restrict__ ex,
                             int* __restrict__ bsum, int N){
  __shared__ int tmp[256];
  int t = threadIdx.x;
  int i = blockIdx.x*256 + t;
  int v = (i < N) ? cnt[i] : 0;
  tmp[t] = v; __syncthreads();
  for (int off = 1; off < 256; off <<= 1){
    int u = (t >= off) ? tmp[t-off] : 0;
    __syncthreads();
    tmp[t] += u;
    __syncthreads();
  }
  if (i < N) ex[i] = tmp[t] - v;
  if (t == 255) bsum[blockIdx.x] = tmp[255];
}

__global__ void k_scan_tops(int* __restrict__ bsum, int nb){
  __shared__ int tmp[256];
  int t = threadIdx.x;
  int v = (t < nb) ? bsum[t] : 0;
  tmp[t] = v; __syncthreads();
  for (int off = 1; off < 256; off <<= 1){
    int u = (t >= off) ? tmp[t-off] : 0;
    __syncthreads();
    tmp[t] += u;
    __syncthreads();
  }
  if (t < nb) bsum[t] = tmp[t] - v;
}

__global__ void k_scan_add(int* __restrict__ row_start, const int* __restrict__ bsum,
                           int N, int total){
  int i = blockIdx.x*256 + threadIdx.x;
  if (i < N) row_start[i] += bsum[blockIdx.x];
  if (i == 0) row_start[N] = total;
}

__global__ void k_scatter(const int* __restrict__ src, const int* __restrict__ dst,
                          int E, int N, const int* __restrict__ row_start,
                          int* __restrict__ cursor, int* __restrict__ edge_src){
  int i = blockIdx.x*blockDim.x + threadIdx.x;
  if (i < E){
    int d = dst[i];
    int p = atomicAdd(&cursor[d], 1);
    edge_src[row_start[d] + p] = src[i];
  } else if (i < E + N){
    int n = i - E;
    int p = atomicAdd(&cursor[n], 1);
    edge_src[row_start[n] + p] = n;
  }
}

// ---------------- W split: W[K][Nw] fp32 -> WT[Nw][3K] f16 = [Wh | Wh | Wl] ----------------
__global__ void k_splitW(const float* __restrict__ W, _Float16* __restrict__ WT,
                         int K, int Nw){
  int id = blockIdx.x*blockDim.x + threadIdx.x;
  if (id >= K*Nw) return;
  int n = id / K, k = id % K;
  float w = W[(size_t)k*Nw + n];
  _Float16 h = (_Float16)w;
  _Float16 l = (_Float16)(w - (float)h);
  size_t base = (size_t)n*3*K;
  WT[base + k]       = h;
  WT[base + K + k]   = h;
  WT[base + 2*K + k] = l;
}

// ---------------- split-f16 MFMA GEMM ----------------
// C[M][Nw] = A[M][K] @ W + bias  computed as Ah@Wh + Al@Wh + Ah@Wl (K' = 3K)
// A staged+converted in-kernel; WT pre-split [Nw][3K].
// tile 128x128, BK=64, 4 waves (2x2), each wave 64x64 (4x4 frags of 16x16x32 f16 MFMA).
__global__ __launch_bounds__(256, 2)
void k_gemm_split(const float* __restrict__ A, const _Float16* __restrict__ WT,
                  const float* __restrict__ bias, float* __restrict__ C,
                  int M, int K, int Nw){
  __shared__ _Float16 sA[128*72];
  __shared__ _Float16 sB[128*72];
  const int tid  = threadIdx.x;
  const int lane = tid & 63;
  const int wid  = tid >> 6;
  const int wm   = wid >> 1, wn = wid & 1;
  const int m0   = blockIdx.x * 128;
  const int n0   = blockIdx.y * 128;
  const int K3   = 3*K;

  f32x4 acc[4][4];
  #pragma unroll
  for (int i = 0; i < 4; ++i)
    #pragma unroll
    for (int j = 0; j < 4; ++j)
      acc[i][j] = (f32x4){0.f,0.f,0.f,0.f};

  const int l15 = lane & 15;
  const int lhi = lane >> 4;          // 0..3

  const int nt = K3/64;
  for (int t = 0; t < nt; ++t){
    const int v  = (t*64)/K;          // 0:hi 1:lo 2:hi (A side)
    const int kb = (t*64)%K;
    // ---- stage A: 128 rows x 64 fp32 -> f16 (hi or lo) ----
    #pragma unroll
    for (int it = 0; it < 8; ++it){
      int idx = it*256 + tid;         // 0..2047
      int r = idx >> 4, c4 = idx & 15;
      int gr = m0 + r;
      fvec4 f = (fvec4){0.f,0.f,0.f,0.f};
      if (gr < M) f = *(const fvec4*)&A[(size_t)gr*K + kb + c4*4];
      half4 hv;
      #pragma unroll
      for (int q = 0; q < 4; ++q){
        float x = f[q];
        _Float16 hh = (_Float16)x;
        hv[q] = (v == 1) ? (_Float16)(x - (float)hh) : hh;
      }
      *(half4*)&sA[r*72 + c4*4] = hv;
    }
    // ---- stage B: 128 rows x 64 f16 from WT ----
    #pragma unroll
    for (int it = 0; it < 4; ++it){
      int idx = it*256 + tid;         // 0..1023
      int r = idx >> 3, c8 = idx & 7;
      half8 w = *(const half8*)&WT[(size_t)(n0 + r)*K3 + t*64 + c8*8];
      *(half8*)&sB[r*72 + c8*8] = w;
    }
    __syncthreads();
    // ---- compute ----
    #pragma unroll
    for (int ks = 0; ks < 64; ks += 32){
      half8 a[4], b[4];
      #pragma unroll
      for (int fm = 0; fm < 4; ++fm)
        a[fm] = *(const half8*)&sA[(wm*64 + fm*16 + l15)*72 + ks + 8*lhi];
      #pragma unroll
      for (int fn = 0; fn < 4; ++fn)
        b[fn] = *(const half8*)&sB[(wn*64 + fn*16 + l15)*72 + ks + 8*lhi];
      #pragma unroll
      for (int fm = 0; fm < 4; ++fm)
        #pragma unroll
        for (int fn = 0; fn < 4; ++fn)
          acc[fm][fn] = __builtin_amdgcn_mfma_f32_16x16x32_f16(a[fm], b[fn], acc[fm][fn], 0, 0, 0);
    }
    __syncthreads();
  }
  // ---- epilogue: D col = lane&15, row = (lane>>4)*4 + reg ----
  #pragma unroll
  for (int fm = 0; fm < 4; ++fm){
    #pragma unroll
    for (int fn = 0; fn < 4; ++fn){
      int col = n0 + wn*64 + fn*16 + l15;
      float bv = bias[col];
      #pragma unroll
      for (int q = 0; q < 4; ++q){
        int row = m0 + wm*64 + fm*16 + lhi*4 + q;
        if (row < M) C[(size_t)row*Nw + col] = acc[fm][fn][q] + bv;
      }
    }
  }
}

// ---------------- GATv2 aggregation: one wave per dst node ----------------
template<int HC, int C>
__global__ __launch_bounds__(256) void k_gat_agg(const float* __restrict__ xl,
                                                 const float* __restrict__ xr,
                                                 const float* __restrict__ att,
                                                 const float* __restrict__ bias,
                                                 const int* __restrict__ row_start,
                                                 const int* __restrict__ edge_src,
                                                 float* __restrict__ out,
                                                 int N, int apply_elu){
  constexpr int VPL = HC/64;
  constexpr int H = HC/C;
  int wid = (int)(((size_t)blockIdx.x * blockDim.x + threadIdx.x) >> 6);
  int lane = threadIdx.x & 63;
  if (wid >= N) return;
  float attr[VPL], xrr[VPL];
  #pragma unroll
  for (int j = 0; j < VPL; ++j){
    attr[j] = att[j*64 + lane];
    xrr[j]  = xr[(size_t)wid*HC + j*64 + lane];
  }
  float m[H], s[H], acc[VPL];
  #pragma unroll
  for (int h = 0; h < H; ++h){ m[h] = -INFINITY; s[h] = 0.f; }
  #pragma unroll
  for (int j = 0; j < VPL; ++j) acc[j] = 0.f;

  int e0 = row_start[wid], e1 = row_start[wid+1];
  for (int e = e0; e < e1; ++e){
    int sn = edge_src[e];
    float xlv[VPL], tv[VPL];
    #pragma unroll
    for (int j = 0; j < VPL; ++j){
      float xv = xl[(size_t)sn*HC + j*64 + lane];
      xlv[j] = xv;
      float v = xv + xrr[j];
      v = (v > 0.f) ? v : NEG_SLOPE*v;
      tv[j] = v * attr[j];
    }
    #pragma unroll
    for (int off = 32; off > 0; off >>= 1){
      #pragma unroll
      for (int j = 0; j < VPL; ++j) tv[j] += __shfl_xor(tv[j], off, 64);
    }
    float logit[H];
    #pragma unroll
    for (int h = 0; h < H; ++h) logit[h] = 0.f;
    #pragma unroll
    for (int j = 0; j < VPL; ++j) logit[(j*64)/C] += tv[j];

    float wo[H], p[H];
    #pragma unroll
    for (int h = 0; h < H; ++h){
      float nm = fmaxf(m[h], logit[h]);
      wo[h] = __expf(m[h] - nm);
      p[h]  = __expf(logit[h] - nm);
      s[h]  = s[h]*wo[h] + p[h];
      m[h]  = nm;
    }
    #pragma unroll
    for (int j = 0; j < VPL; ++j){
      int h = (j*64)/C;
      acc[j] = acc[j]*wo[h] + p[h]*xlv[j];
    }
  }
  #pragma unroll
  for (int j = 0; j < VPL; ++j){
    int h = (j*64)/C;
    int g = j*64 + lane;
    float o = acc[j]/s[h] + bias[g];
    if (apply_elu) o = (o > 0.f) ? o : (__expf(o) - 1.f);
    out[(size_t)wid*HC + g] = o;
  }
}

// ---------------- global mean pool ----------------
__global__ void k_pool(const float* __restrict__ h, const int* __restrict__ batch,
                       float* __restrict__ pool, int* __restrict__ gcnt, int N){
  int wid = (int)(((size_t)blockIdx.x * blockDim.x + threadIdx.x) >> 6);
  int lane = threadIdx.x & 63;
  if (wid >= N) return;
  int g = batch[wid];
  #pragma unroll
  for (int j = 0; j < 2; ++j)
    atomicAdd(&pool[(size_t)g*128 + j*64 + lane], h[(size_t)wid*128 + j*64 + lane]);
  if (lane == 0) atomicAdd(&gcnt[g], 1);
}

__global__ void k_pool_div(const float* __restrict__ pool, const int* __restrict__ gcnt,
                           float* __restrict__ out, int total){
  int i = blockIdx.x*blockDim.x + threadIdx.x;
  if (i < total) out[i] = pool[i] / fmaxf((float)gcnt[i >> 7], 1.f);
}

extern "C" void kernel_launch(void* const* d_in, const int* in_sizes, int n_in,
                              void* d_out, int out_size, void* d_ws, size_t ws_size,
                              hipStream_t stream){
  const float* x    = (const float*)d_in[0];
  const int*   ei   = (const int*)  d_in[1];
  const int*   batch= (const int*)  d_in[2];
  const float* Wl1  = (const float*)d_in[3];
  const float* bl1  = (const float*)d_in[4];
  const float* Wr1  = (const float*)d_in[5];
  const float* br1  = (const float*)d_in[6];
  const float* att1 = (const float*)d_in[7];
  const float* b1   = (const float*)d_in[8];
  const float* Wl2  = (const float*)d_in[9];
  const float* bl2  = (const float*)d_in[10];
  const float* Wr2  = (const float*)d_in[11];
  const float* br2  = (const float*)d_in[12];
  const float* att2 = (const float*)d_in[13];
  const float* b2   = (const float*)d_in[14];
  const float* Wl3  = (const float*)d_in[15];
  const float* bl3  = (const float*)d_in[16];
  const float* Wr3  = (const float*)d_in[17];
  const float* br3  = (const float*)d_in[18];
  const float* att3 = (const float*)d_in[19];
  const float* b3   = (const float*)d_in[20];

  int N  = in_sizes[2];          // 50000
  int E  = in_sizes[1] / 2;      // 800000
  int NG = out_size / 128;       // 1000
  const int* esrc = ei;
  const int* edst = ei + E;
  int Mpad = ((N + 127)/128)*128;

  size_t off = 0;
  char* base = (char*)d_ws;
  auto alloc = [&](size_t bytes)->void*{
    void* p = base + off;
    off += (bytes + 255) & ~(size_t)255;
    return p;
  };
  float* XL  = (float*)alloc((size_t)Mpad*256*sizeof(float));
  float* XR  = (float*)alloc((size_t)Mpad*256*sizeof(float));
  float* Hb  = (float*)alloc((size_t)Mpad*256*sizeof(float));
  _Float16* WTl = (_Float16*)alloc((size_t)256*768*sizeof(_Float16));
  _Float16* WTr = (_Float16*)alloc((size_t)256*768*sizeof(_Float16));
  int* row_start = (int*)alloc(((size_t)N+1)*sizeof(int));
  int* edge_src  = (int*)alloc((size_t)(E+N)*sizeof(int));
  int* cnt       = (int*)alloc((size_t)N*sizeof(int));
  int* bsum      = (int*)alloc(256*sizeof(int));
  float* pool    = (float*)alloc((size_t)NG*128*sizeof(float));
  int* gcnt      = (int*)alloc((size_t)NG*sizeof(int));
  (void)ws_size; (void)n_in;

  int EN = E + N;
  int nb = (N + 255) / 256;

  // CSR build
  hipMemsetAsync(cnt, 0, (size_t)N*sizeof(int), stream);
  k_count<<<(EN+255)/256, 256, 0, stream>>>(edst, E, N, cnt);
  k_scan_block<<<nb, 256, 0, stream>>>(cnt, row_start, bsum, N);
  k_scan_tops<<<1, 256, 0, stream>>>(bsum, nb);
  k_scan_add<<<nb, 256, 0, stream>>>(row_start, bsum, N, EN);
  hipMemsetAsync(cnt, 0, (size_t)N*sizeof(int), stream);
  k_scatter<<<(EN+255)/256, 256, 0, stream>>>(esrc, edst, E, N, row_start, cnt, edge_src);

  dim3 blk(256);
  int agg_blocks = (N + 3) / 4;
  dim3 gemm_g2(Mpad/128, 2);     // Nw = 256
  dim3 gemm_g1(Mpad/128, 1);     // Nw = 128

  // ---- Layer 1: K=64 -> 256 ----
  k_splitW<<<(64*256+255)/256, blk, 0, stream>>>(Wl1, WTl, 64, 256);
  k_splitW<<<(64*256+255)/256, blk, 0, stream>>>(Wr1, WTr, 64, 256);
  k_gemm_split<<<gemm_g2, blk, 0, stream>>>(x, WTl, bl1, XL, N, 64, 256);
  k_gemm_split<<<gemm_g2, blk, 0, stream>>>(x, WTr, br1, XR, N, 64, 256);
  k_gat_agg<256,64><<<agg_blocks, blk, 0, stream>>>(XL, XR, att1, b1, row_start, edge_src, Hb, N, 1);

  // ---- Layer 2: K=256 -> 256 ----
  k_splitW<<<(256*256+255)/256, blk, 0, stream>>>(Wl2, WTl, 256, 256);
  k_splitW<<<(256*256+255)/256, blk, 0, stream>>>(Wr2, WTr, 256, 256);
  k_gemm_split<<<gemm_g2, blk, 0, stream>>>(Hb, WTl, bl2, XL, N, 256, 256);
  k_gemm_split<<<gemm_g2, blk, 0, stream>>>(Hb, WTr, br2, XR, N, 256, 256);
  k_gat_agg<256,64><<<agg_blocks, blk, 0, stream>>>(XL, XR, att2, b2, row_start, edge_src, Hb, N, 1);

  // ---- Layer 3: K=256 -> 128, 1 head, no concat, no elu ----
  k_splitW<<<(256*128+255)/256, blk, 0, stream>>>(Wl3, WTl, 256, 128);
  k_splitW<<<(256*128+255)/256, blk, 0, stream>>>(Wr3, WTr, 256, 128);
  k_gemm_split<<<gemm_g1, blk, 0, stream>>>(Hb, WTl, bl3, XL, N, 256, 128);
  k_gemm_split<<<gemm_g1, blk, 0, stream>>>(Hb, WTr, br3, XR, N, 256, 128);
  k_gat_agg<128,128><<<agg_blocks, blk, 0, stream>>>(XL, XR, att3, b3, row_start, edge_src, Hb, N, 0);

  // ---- Global mean pool ----
  hipMemsetAsync(pool, 0, (size_t)NG*128*sizeof(float), stream);
  hipMemsetAsync(gcnt, 0, (size_t)NG*sizeof(int), stream);
  k_pool<<<agg_blocks, blk, 0, stream>>>(Hb, batch, pool, gcnt, N);
  k_pool_div<<<(NG*128+255)/256, 256, 0, stream>>>(pool, gcnt, (float*)d_out, NG*128);
}

// Round 3
// 864.547 us; speedup vs baseline: 2.6098x; 1.2809x over previous
//
#include <hip/hip_runtime.h>
#include <math.h>

#define NEG_SLOPE 0.2f

typedef _Float16 half8 __attribute__((ext_vector_type(8)));
typedef _Float16 half4 __attribute__((ext_vector_type(4)));
typedef float    f32x4 __attribute__((ext_vector_type(4)));
typedef float    fvec4 __attribute__((ext_vector_type(4)));
typedef float    fvec2 __attribute__((ext_vector_type(2)));

// ---------------- CSR build ----------------
__global__ void k_count(const int* __restrict__ dst, int E, int N, int* __restrict__ cnt){
  int i = blockIdx.x*blockDim.x + threadIdx.x;
  if (i < E) atomicAdd(&cnt[dst[i]], 1);
  else if (i < E + N) atomicAdd(&cnt[i - E], 1);   // self loops
}

__global__ void k_scan_block(const int* __restrict__ cnt, int* __restrict__ ex,
                             int* __restrict__ bsum, int N){
  __shared__ int tmp[256];
  int t = threadIdx.x;
  int i = blockIdx.x*256 + t;
  int v = (i < N) ? cnt[i] : 0;
  tmp[t] = v; __syncthreads();
  for (int off = 1; off < 256; off <<= 1){
    int u = (t >= off) ? tmp[t-off] : 0;
    __syncthreads();
    tmp[t] += u;
    __syncthreads();
  }
  if (i < N) ex[i] = tmp[t] - v;
  if (t == 255) bsum[blockIdx.x] = tmp[255];
}

__global__ void k_scan_tops(int* __restrict__ bsum, int nb){
  __shared__ int tmp[256];
  int t = threadIdx.x;
  int v = (t < nb) ? bsum[t] : 0;
  tmp[t] = v; __syncthreads();
  for (int off = 1; off < 256; off <<= 1){
    int u = (t >= off) ? tmp[t-off] : 0;
    __syncthreads();
    tmp[t] += u;
    __syncthreads();
  }
  if (t < nb) bsum[t] = tmp[t] - v;
}

__global__ void k_scan_add(int* __restrict__ row_start, const int* __restrict__ bsum,
                           int N, int total){
  int i = blockIdx.x*256 + threadIdx.x;
  if (i < N) row_start[i] += bsum[blockIdx.x];
  if (i == 0) row_start[N] = total;
}

__global__ void k_scatter(const int* __restrict__ src, const int* __restrict__ dst,
                          int E, int N, const int* __restrict__ row_start,
                          int* __restrict__ cursor, int* __restrict__ edge_src){
  int i = blockIdx.x*blockDim.x + threadIdx.x;
  if (i < E){
    int d = dst[i];
    int p = atomicAdd(&cursor[d], 1);
    edge_src[row_start[d] + p] = src[i];
  } else if (i < E + N){
    int n = i - E;
    int p = atomicAdd(&cursor[n], 1);
    edge_src[row_start[n] + p] = n;
  }
}

// ---------------- W split: W[K][Nw] fp32 -> WT[Nw][3K] f16 = [Wh | Wh | Wl] ----------------
__global__ void k_splitW(const float* __restrict__ W, _Float16* __restrict__ WT,
                         int K, int Nw){
  int id = blockIdx.x*blockDim.x + threadIdx.x;
  if (id >= K*Nw) return;
  int n = id / K, k = id % K;
  float w = W[(size_t)k*Nw + n];
  _Float16 h = (_Float16)w;
  _Float16 l = (_Float16)(w - (float)h);
  size_t base = (size_t)n*3*K;
  WT[base + k]       = h;
  WT[base + K + k]   = h;
  WT[base + 2*K + k] = l;
}

// ---------------- split-f16 MFMA GEMM ----------------
__global__ __launch_bounds__(256, 2)
void k_gemm_split(const float* __restrict__ A, const _Float16* __restrict__ WT,
                  const float* __restrict__ bias, float* __restrict__ C,
                  int M, int K, int Nw){
  __shared__ _Float16 sA[128*72];
  __shared__ _Float16 sB[128*72];
  const int tid  = threadIdx.x;
  const int lane = tid & 63;
  const int wid  = tid >> 6;
  const int wm   = wid >> 1, wn = wid & 1;
  const int m0   = blockIdx.x * 128;
  const int n0   = blockIdx.y * 128;
  const int K3   = 3*K;

  f32x4 acc[4][4];
  #pragma unroll
  for (int i = 0; i < 4; ++i)
    #pragma unroll
    for (int j = 0; j < 4; ++j)
      acc[i][j] = (f32x4){0.f,0.f,0.f,0.f};

  const int l15 = lane & 15;
  const int lhi = lane >> 4;

  const int nt = K3/64;
  for (int t = 0; t < nt; ++t){
    const int v  = (t*64)/K;          // 0:hi 1:lo 2:hi (A side)
    const int kb = (t*64)%K;
    #pragma unroll
    for (int it = 0; it < 8; ++it){
      int idx = it*256 + tid;
      int r = idx >> 4, c4 = idx & 15;
      int gr = m0 + r;
      fvec4 f = (fvec4){0.f,0.f,0.f,0.f};
      if (gr < M) f = *(const fvec4*)&A[(size_t)gr*K + kb + c4*4];
      half4 hv;
      #pragma unroll
      for (int q = 0; q < 4; ++q){
        float x = f[q];
        _Float16 hh = (_Float16)x;
        hv[q] = (v == 1) ? (_Float16)(x - (float)hh) : hh;
      }
      *(half4*)&sA[r*72 + c4*4] = hv;
    }
    #pragma unroll
    for (int it = 0; it < 4; ++it){
      int idx = it*256 + tid;
      int r = idx >> 3, c8 = idx & 7;
      half8 w = *(const half8*)&WT[(size_t)(n0 + r)*K3 + t*64 + c8*8];
      *(half8*)&sB[r*72 + c8*8] = w;
    }
    __syncthreads();
    #pragma unroll
    for (int ks = 0; ks < 64; ks += 32){
      half8 a[4], b[4];
      #pragma unroll
      for (int fm = 0; fm < 4; ++fm)
        a[fm] = *(const half8*)&sA[(wm*64 + fm*16 + l15)*72 + ks + 8*lhi];
      #pragma unroll
      for (int fn = 0; fn < 4; ++fn)
        b[fn] = *(const half8*)&sB[(wn*64 + fn*16 + l15)*72 + ks + 8*lhi];
      #pragma unroll
      for (int fm = 0; fm < 4; ++fm)
        #pragma unroll
        for (int fn = 0; fn < 4; ++fn)
          acc[fm][fn] = __builtin_amdgcn_mfma_f32_16x16x32_f16(a[fm], b[fn], acc[fm][fn], 0, 0, 0);
    }
    __syncthreads();
  }
  #pragma unroll
  for (int fm = 0; fm < 4; ++fm){
    #pragma unroll
    for (int fn = 0; fn < 4; ++fn){
      int col = n0 + wn*64 + fn*16 + l15;
      float bv = bias[col];
      #pragma unroll
      for (int q = 0; q < 4; ++q){
        int row = m0 + wm*64 + fm*16 + lhi*4 + q;
        if (row < M) C[(size_t)row*Nw + col] = acc[fm][fn][q] + bv;
      }
    }
  }
}

// ---------------- GATv2 aggregation v2 ----------------
// one wave per dst node; lane -> head g = lane/GROUP, owns VEC consecutive
// channels: ch = g*C + (lane%GROUP)*VEC. Head-local scalar logit reduction
// over GROUP lanes; pairwise (2-edge) online softmax.
template<int HC, int C>
__global__ __launch_bounds__(256) void k_gat_agg(const float* __restrict__ xl,
                                                 const float* __restrict__ xr,
                                                 const float* __restrict__ att,
                                                 const float* __restrict__ bias,
                                                 const int* __restrict__ row_start,
                                                 const int* __restrict__ edge_src,
                                                 float* __restrict__ out,
                                                 int N, int apply_elu){
  constexpr int VEC   = HC/64;     // floats per lane
  constexpr int GROUP = C/VEC;     // lanes per head
  int wid = (int)(((size_t)blockIdx.x * blockDim.x + threadIdx.x) >> 6);
  int lane = threadIdx.x & 63;
  if (wid >= N) return;

  const int ch = (lane/GROUP)*C + (lane%GROUP)*VEC;   // my channel base

  float attv[VEC], xrrv[VEC], acc[VEC];
  {
    if constexpr (VEC == 4){
      *(fvec4*)attv = *(const fvec4*)&att[ch];
      *(fvec4*)xrrv = *(const fvec4*)&xr[(size_t)wid*HC + ch];
    } else {
      *(fvec2*)attv = *(const fvec2*)&att[ch];
      *(fvec2*)xrrv = *(const fvec2*)&xr[(size_t)wid*HC + ch];
    }
  }
  #pragma unroll
  for (int q = 0; q < VEC; ++q) acc[q] = 0.f;
  float m = -INFINITY, s = 0.f;

  const int e0 = row_start[wid], e1 = row_start[wid+1];

  auto loadrow = [&](int sn, float* dstv){
    if constexpr (VEC == 4) *(fvec4*)dstv = *(const fvec4*)&xl[(size_t)sn*HC + ch];
    else                    *(fvec2*)dstv = *(const fvec2*)&xl[(size_t)sn*HC + ch];
  };
  auto edge_logit = [&](const float* xv)->float{
    float tv = 0.f;
    #pragma unroll
    for (int q = 0; q < VEC; ++q){
      float v = xv[q] + xrrv[q];
      v = (v > 0.f) ? v : NEG_SLOPE*v;
      tv = fmaf(v, attv[q], tv);
    }
    #pragma unroll
    for (int off = GROUP/2; off > 0; off >>= 1)
      tv += __shfl_xor(tv, off, 64);
    return tv;
  };

  int e = e0;
  // pairwise main loop
  for (; e + 1 < e1; e += 2){
    int sa = edge_src[e], sb = edge_src[e+1];
    float xa[VEC], xb[VEC];
    loadrow(sa, xa);
    loadrow(sb, xb);
    float ta = edge_logit(xa);
    float tb = edge_logit(xb);
    float nm = fmaxf(fmaxf(m, ta), tb);
    float wo = __expf(m - nm);
    float pa = __expf(ta - nm);
    float pb = __expf(tb - nm);
    s = s*wo + pa + pb;
    m = nm;
    #pragma unroll
    for (int q = 0; q < VEC; ++q)
      acc[q] = fmaf(pa, xa[q], fmaf(pb, xb[q], acc[q]*wo));
  }
  // tail edge
  if (e < e1){
    int sa = edge_src[e];
    float xa[VEC];
    loadrow(sa, xa);
    float ta = edge_logit(xa);
    float nm = fmaxf(m, ta);
    float wo = __expf(m - nm);
    float pa = __expf(ta - nm);
    s = s*wo + pa;
    m = nm;
    #pragma unroll
    for (int q = 0; q < VEC; ++q)
      acc[q] = fmaf(pa, xa[q], acc[q]*wo);
  }

  float inv = 1.f / s;
  float ov[VEC];
  #pragma unroll
  for (int q = 0; q < VEC; ++q){
    float o = acc[q]*inv + bias[ch + q];
    if (apply_elu) o = (o > 0.f) ? o : (__expf(o) - 1.f);
    ov[q] = o;
  }
  if constexpr (VEC == 4) *(fvec4*)&out[(size_t)wid*HC + ch] = *(fvec4*)ov;
  else                    *(fvec2*)&out[(size_t)wid*HC + ch] = *(fvec2*)ov;
}

// ---------------- global mean pool ----------------
__global__ void k_pool(const float* __restrict__ h, const int* __restrict__ batch,
                       float* __restrict__ pool, int* __restrict__ gcnt, int N){
  int wid = (int)(((size_t)blockIdx.x * blockDim.x + threadIdx.x) >> 6);
  int lane = threadIdx.x & 63;
  if (wid >= N) return;
  int g = batch[wid];
  #pragma unroll
  for (int j = 0; j < 2; ++j)
    atomicAdd(&pool[(size_t)g*128 + j*64 + lane], h[(size_t)wid*128 + j*64 + lane]);
  if (lane == 0) atomicAdd(&gcnt[g], 1);
}

__global__ void k_pool_div(const float* __restrict__ pool, const int* __restrict__ gcnt,
                           float* __restrict__ out, int total){
  int i = blockIdx.x*blockDim.x + threadIdx.x;
  if (i < total) out[i] = pool[i] / fmaxf((float)gcnt[i >> 7], 1.f);
}

extern "C" void kernel_launch(void* const* d_in, const int* in_sizes, int n_in,
                              void* d_out, int out_size, void* d_ws, size_t ws_size,
                              hipStream_t stream){
  const float* x    = (const float*)d_in[0];
  const int*   ei   = (const int*)  d_in[1];
  const int*   batch= (const int*)  d_in[2];
  const float* Wl1  = (const float*)d_in[3];
  const float* bl1  = (const float*)d_in[4];
  const float* Wr1  = (const float*)d_in[5];
  const float* br1  = (const float*)d_in[6];
  const float* att1 = (const float*)d_in[7];
  const float* b1   = (const float*)d_in[8];
  const float* Wl2  = (const float*)d_in[9];
  const float* bl2  = (const float*)d_in[10];
  const float* Wr2  = (const float*)d_in[11];
  const float* br2  = (const float*)d_in[12];
  const float* att2 = (const float*)d_in[13];
  const float* b2   = (const float*)d_in[14];
  const float* Wl3  = (const float*)d_in[15];
  const float* bl3  = (const float*)d_in[16];
  const float* Wr3  = (const float*)d_in[17];
  const float* br3  = (const float*)d_in[18];
  const float* att3 = (const float*)d_in[19];
  const float* b3   = (const float*)d_in[20];

  int N  = in_sizes[2];          // 50000
  int E  = in_sizes[1] / 2;      // 800000
  int NG = out_size / 128;       // 1000
  const int* esrc = ei;
  const int* edst = ei + E;
  int Mpad = ((N + 127)/128)*128;

  size_t off = 0;
  char* base = (char*)d_ws;
  auto alloc = [&](size_t bytes)->void*{
    void* p = base + off;
    off += (bytes + 255) & ~(size_t)255;
    return p;
  };
  float* XL  = (float*)alloc((size_t)Mpad*256*sizeof(float));
  float* XR  = (float*)alloc((size_t)Mpad*256*sizeof(float));
  float* Hb  = (float*)alloc((size_t)Mpad*256*sizeof(float));
  _Float16* WTl = (_Float16*)alloc((size_t)256*768*sizeof(_Float16));
  _Float16* WTr = (_Float16*)alloc((size_t)256*768*sizeof(_Float16));
  int* row_start = (int*)alloc(((size_t)N+1)*sizeof(int));
  int* edge_src  = (int*)alloc((size_t)(E+N)*sizeof(int));
  int* cnt       = (int*)alloc((size_t)N*sizeof(int));
  int* bsum      = (int*)alloc(256*sizeof(int));
  float* pool    = (float*)alloc((size_t)NG*128*sizeof(float));
  int* gcnt      = (int*)alloc((size_t)NG*sizeof(int));
  (void)ws_size; (void)n_in;

  int EN = E + N;
  int nb = (N + 255) / 256;

  // CSR build
  hipMemsetAsync(cnt, 0, (size_t)N*sizeof(int), stream);
  k_count<<<(EN+255)/256, 256, 0, stream>>>(edst, E, N, cnt);
  k_scan_block<<<nb, 256, 0, stream>>>(cnt, row_start, bsum, N);
  k_scan_tops<<<1, 256, 0, stream>>>(bsum, nb);
  k_scan_add<<<nb, 256, 0, stream>>>(row_start, bsum, N, EN);
  hipMemsetAsync(cnt, 0, (size_t)N*sizeof(int), stream);
  k_scatter<<<(EN+255)/256, 256, 0, stream>>>(esrc, edst, E, N, row_start, cnt, edge_src);

  dim3 blk(256);
  int agg_blocks = (N + 3) / 4;
  dim3 gemm_g2(Mpad/128, 2);     // Nw = 256
  dim3 gemm_g1(Mpad/128, 1);     // Nw = 128

  // ---- Layer 1: K=64 -> 256 ----
  k_splitW<<<(64*256+255)/256, blk, 0, stream>>>(Wl1, WTl, 64, 256);
  k_splitW<<<(64*256+255)/256, blk, 0, stream>>>(Wr1, WTr, 64, 256);
  k_gemm_split<<<gemm_g2, blk, 0, stream>>>(x, WTl, bl1, XL, N, 64, 256);
  k_gemm_split<<<gemm_g2, blk, 0, stream>>>(x, WTr, br1, XR, N, 64, 256);
  k_gat_agg<256,64><<<agg_blocks, blk, 0, stream>>>(XL, XR, att1, b1, row_start, edge_src, Hb, N, 1);

  // ---- Layer 2: K=256 -> 256 ----
  k_splitW<<<(256*256+255)/256, blk, 0, stream>>>(Wl2, WTl, 256, 256);
  k_splitW<<<(256*256+255)/256, blk, 0, stream>>>(Wr2, WTr, 256, 256);
  k_gemm_split<<<gemm_g2, blk, 0, stream>>>(Hb, WTl, bl2, XL, N, 256, 256);
  k_gemm_split<<<gemm_g2, blk, 0, stream>>>(Hb, WTr, br2, XR, N, 256, 256);
  k_gat_agg<256,64><<<agg_blocks, blk, 0, stream>>>(XL, XR, att2, b2, row_start, edge_src, Hb, N, 1);

  // ---- Layer 3: K=256 -> 128, 1 head, no concat, no elu ----
  k_splitW<<<(256*128+255)/256, blk, 0, stream>>>(Wl3, WTl, 256, 128);
  k_splitW<<<(256*128+255)/256, blk, 0, stream>>>(Wr3, WTr, 256, 128);
  k_gemm_split<<<gemm_g1, blk, 0, stream>>>(Hb, WTl, bl3, XL, N, 256, 128);
  k_gemm_split<<<gemm_g1, blk, 0, stream>>>(Hb, WTr, br3, XR, N, 256, 128);
  k_gat_agg<128,128><<<agg_blocks, blk, 0, stream>>>(XL, XR, att3, b3, row_start, edge_src, Hb, N, 0);

  // ---- Global mean pool ----
  hipMemsetAsync(pool, 0, (size_t)NG*128*sizeof(float), stream);
  hipMemsetAsync(gcnt, 0, (size_t)NG*sizeof(int), stream);
  k_pool<<<agg_blocks, blk, 0, stream>>>(Hb, batch, pool, gcnt, N);
  k_pool_div<<<(NG*128+255)/256, 256, 0, stream>>>(pool, gcnt, (float*)d_out, NG*128);
}

// Round 4
// 697.755 us; speedup vs baseline: 3.2337x; 1.2390x over previous
//
#include <hip/hip_runtime.h>
#include <math.h>

#define NEG_SLOPE 0.2f

typedef _Float16 half8 __attribute__((ext_vector_type(8)));
typedef _Float16 half4 __attribute__((ext_vector_type(4)));
typedef _Float16 half2v __attribute__((ext_vector_type(2)));
typedef float    f32x4 __attribute__((ext_vector_type(4)));
typedef float    fvec4 __attribute__((ext_vector_type(4)));
typedef float    fvec2 __attribute__((ext_vector_type(2)));

// ---------------- CSR build ----------------
__global__ void k_count(const int* __restrict__ dst, int E, int N, int* __restrict__ cnt){
  int i = blockIdx.x*blockDim.x + threadIdx.x;
  if (i < E) atomicAdd(&cnt[dst[i]], 1);
  else if (i < E + N) atomicAdd(&cnt[i - E], 1);   // self loops
}

__global__ void k_scan_block(const int* __restrict__ cnt, int* __restrict__ ex,
                             int* __restrict__ bsum, int N){
  __shared__ int tmp[256];
  int t = threadIdx.x;
  int i = blockIdx.x*256 + t;
  int v = (i < N) ? cnt[i] : 0;
  tmp[t] = v; __syncthreads();
  for (int off = 1; off < 256; off <<= 1){
    int u = (t >= off) ? tmp[t-off] : 0;
    __syncthreads();
    tmp[t] += u;
    __syncthreads();
  }
  if (i < N) ex[i] = tmp[t] - v;
  if (t == 255) bsum[blockIdx.x] = tmp[255];
}

__global__ void k_scan_tops(int* __restrict__ bsum, int nb){
  __shared__ int tmp[256];
  int t = threadIdx.x;
  int v = (t < nb) ? bsum[t] : 0;
  tmp[t] = v; __syncthreads();
  for (int off = 1; off < 256; off <<= 1){
    int u = (t >= off) ? tmp[t-off] : 0;
    __syncthreads();
    tmp[t] += u;
    __syncthreads();
  }
  if (t < nb) bsum[t] = tmp[t] - v;
}

__global__ void k_scan_add(int* __restrict__ row_start, const int* __restrict__ bsum,
                           int N, int total){
  int i = blockIdx.x*256 + threadIdx.x;
  if (i < N) row_start[i] += bsum[blockIdx.x];
  if (i == 0) row_start[N] = total;
}

__global__ void k_scatter(const int* __restrict__ src, const int* __restrict__ dst,
                          int E, int N, const int* __restrict__ row_start,
                          int* __restrict__ cursor, int* __restrict__ edge_src){
  int i = blockIdx.x*blockDim.x + threadIdx.x;
  if (i < E){
    int d = dst[i];
    int p = atomicAdd(&cursor[d], 1);
    edge_src[row_start[d] + p] = src[i];
  } else if (i < E + N){
    int n = i - E;
    int p = atomicAdd(&cursor[n], 1);
    edge_src[row_start[n] + p] = n;
  }
}

// ---------------- W split: W[K][Nw] fp32 -> WT[Nw][3K] f16 = [Wh | Wh | Wl] ----------------
__global__ void k_splitW(const float* __restrict__ W, _Float16* __restrict__ WT,
                         int K, int Nw){
  int id = blockIdx.x*blockDim.x + threadIdx.x;
  if (id >= K*Nw) return;
  int n = id / K, k = id % K;
  float w = W[(size_t)k*Nw + n];
  _Float16 h = (_Float16)w;
  _Float16 l = (_Float16)(w - (float)h);
  size_t base = (size_t)n*3*K;
  WT[base + k]       = h;
  WT[base + K + k]   = h;
  WT[base + 2*K + k] = l;
}

// ---------------- split-f16 MFMA GEMM, merged L/R, f16 output ----------------
// Computes [XL|XR] = A @ [Wl|Wr] + [bl|br] via split-f16 (K'=3K).
// WT = [Nw2][3K] f16 where rows 0..NwHalf-1 are Wl cols, NwHalf.. are Wr cols.
// grid.y = 2*NwHalf/128; isR is block-uniform.
__global__ __launch_bounds__(256, 2)
void k_gemm_split(const float* __restrict__ A, const _Float16* __restrict__ WT,
                  const float* __restrict__ biasL, const float* __restrict__ biasR,
                  _Float16* __restrict__ XL, _Float16* __restrict__ XR,
                  int M, int K, int NwHalf){
  __shared__ _Float16 sA[128*72];
  __shared__ _Float16 sB[128*72];
  const int tid  = threadIdx.x;
  const int lane = tid & 63;
  const int wid  = tid >> 6;
  const int wm   = wid >> 1, wn = wid & 1;
  const int m0   = blockIdx.x * 128;
  const int n0   = blockIdx.y * 128;
  const int K3   = 3*K;

  f32x4 acc[4][4];
  #pragma unroll
  for (int i = 0; i < 4; ++i)
    #pragma unroll
    for (int j = 0; j < 4; ++j)
      acc[i][j] = (f32x4){0.f,0.f,0.f,0.f};

  const int l15 = lane & 15;
  const int lhi = lane >> 4;

  const int nt = K3/64;
  for (int t = 0; t < nt; ++t){
    const int v  = (t*64)/K;          // 0:hi 1:lo 2:hi (A side)
    const int kb = (t*64)%K;
    #pragma unroll
    for (int it = 0; it < 8; ++it){
      int idx = it*256 + tid;
      int r = idx >> 4, c4 = idx & 15;
      int gr = m0 + r;
      fvec4 f = (fvec4){0.f,0.f,0.f,0.f};
      if (gr < M) f = *(const fvec4*)&A[(size_t)gr*K + kb + c4*4];
      half4 hv;
      #pragma unroll
      for (int q = 0; q < 4; ++q){
        float x = f[q];
        _Float16 hh = (_Float16)x;
        hv[q] = (v == 1) ? (_Float16)(x - (float)hh) : hh;
      }
      *(half4*)&sA[r*72 + c4*4] = hv;
    }
    #pragma unroll
    for (int it = 0; it < 4; ++it){
      int idx = it*256 + tid;
      int r = idx >> 3, c8 = idx & 7;
      half8 w = *(const half8*)&WT[(size_t)(n0 + r)*K3 + t*64 + c8*8];
      *(half8*)&sB[r*72 + c8*8] = w;
    }
    __syncthreads();
    #pragma unroll
    for (int ks = 0; ks < 64; ks += 32){
      half8 a[4], b[4];
      #pragma unroll
      for (int fm = 0; fm < 4; ++fm)
        a[fm] = *(const half8*)&sA[(wm*64 + fm*16 + l15)*72 + ks + 8*lhi];
      #pragma unroll
      for (int fn = 0; fn < 4; ++fn)
        b[fn] = *(const half8*)&sB[(wn*64 + fn*16 + l15)*72 + ks + 8*lhi];
      #pragma unroll
      for (int fm = 0; fm < 4; ++fm)
        #pragma unroll
        for (int fn = 0; fn < 4; ++fn)
          acc[fm][fn] = __builtin_amdgcn_mfma_f32_16x16x32_f16(a[fm], b[fn], acc[fm][fn], 0, 0, 0);
    }
    __syncthreads();
  }
  // epilogue: block-uniform L/R select, f16 store
  const bool isR = (n0 >= NwHalf);
  const float* bias = isR ? biasR : biasL;
  _Float16* Xo = isR ? XR : XL;
  const int nbase = isR ? (n0 - NwHalf) : n0;
  #pragma unroll
  for (int fm = 0; fm < 4; ++fm){
    #pragma unroll
    for (int fn = 0; fn < 4; ++fn){
      int c = nbase + wn*64 + fn*16 + l15;
      float bv = bias[c];
      #pragma unroll
      for (int q = 0; q < 4; ++q){
        int row = m0 + wm*64 + fm*16 + lhi*4 + q;
        if (row < M) Xo[(size_t)row*NwHalf + c] = (_Float16)(acc[fm][fn][q] + bv);
      }
    }
  }
}

// ---------------- GATv2 aggregation: f16 gather, head-local reduce ----------------
template<int HC, int C>
__global__ __launch_bounds__(256) void k_gat_agg(const _Float16* __restrict__ xl,
                                                 const _Float16* __restrict__ xr,
                                                 const float* __restrict__ att,
                                                 const float* __restrict__ bias,
                                                 const int* __restrict__ row_start,
                                                 const int* __restrict__ edge_src,
                                                 float* __restrict__ out,
                                                 int N, int apply_elu){
  constexpr int VEC   = HC/64;     // floats per lane
  constexpr int GROUP = C/VEC;     // lanes per head
  int wid = (int)(((size_t)blockIdx.x * blockDim.x + threadIdx.x) >> 6);
  int lane = threadIdx.x & 63;
  if (wid >= N) return;

  const int ch = (lane/GROUP)*C + (lane%GROUP)*VEC;   // my channel base

  float attv[VEC], xrrv[VEC], acc[VEC];
  #pragma unroll
  for (int q = 0; q < VEC; ++q) attv[q] = att[ch + q];
  {
    if constexpr (VEC == 4){
      half4 h = *(const half4*)&xr[(size_t)wid*HC + ch];
      #pragma unroll
      for (int q = 0; q < 4; ++q) xrrv[q] = (float)h[q];
    } else {
      half2v h = *(const half2v*)&xr[(size_t)wid*HC + ch];
      #pragma unroll
      for (int q = 0; q < 2; ++q) xrrv[q] = (float)h[q];
    }
  }
  #pragma unroll
  for (int q = 0; q < VEC; ++q) acc[q] = 0.f;
  float m = -INFINITY, s = 0.f;

  const int e0 = row_start[wid], e1 = row_start[wid+1];

  auto loadrow = [&](int sn, float* dstv){
    if constexpr (VEC == 4){
      half4 h = *(const half4*)&xl[(size_t)sn*HC + ch];
      #pragma unroll
      for (int q = 0; q < 4; ++q) dstv[q] = (float)h[q];
    } else {
      half2v h = *(const half2v*)&xl[(size_t)sn*HC + ch];
      #pragma unroll
      for (int q = 0; q < 2; ++q) dstv[q] = (float)h[q];
    }
  };
  auto edge_logit = [&](const float* xv)->float{
    float tv = 0.f;
    #pragma unroll
    for (int q = 0; q < VEC; ++q){
      float v = xv[q] + xrrv[q];
      v = (v > 0.f) ? v : NEG_SLOPE*v;
      tv = fmaf(v, attv[q], tv);
    }
    #pragma unroll
    for (int off = GROUP/2; off > 0; off >>= 1)
      tv += __shfl_xor(tv, off, 64);
    return tv;
  };

  int e = e0;
  for (; e + 1 < e1; e += 2){
    int sa = edge_src[e], sb = edge_src[e+1];
    float xa[VEC], xb[VEC];
    loadrow(sa, xa);
    loadrow(sb, xb);
    float ta = edge_logit(xa);
    float tb = edge_logit(xb);
    float nm = fmaxf(fmaxf(m, ta), tb);
    float wo = __expf(m - nm);
    float pa = __expf(ta - nm);
    float pb = __expf(tb - nm);
    s = s*wo + pa + pb;
    m = nm;
    #pragma unroll
    for (int q = 0; q < VEC; ++q)
      acc[q] = fmaf(pa, xa[q], fmaf(pb, xb[q], acc[q]*wo));
  }
  if (e < e1){
    int sa = edge_src[e];
    float xa[VEC];
    loadrow(sa, xa);
    float ta = edge_logit(xa);
    float nm = fmaxf(m, ta);
    float wo = __expf(m - nm);
    float pa = __expf(ta - nm);
    s = s*wo + pa;
    m = nm;
    #pragma unroll
    for (int q = 0; q < VEC; ++q)
      acc[q] = fmaf(pa, xa[q], acc[q]*wo);
  }

  float inv = 1.f / s;
  float ov[VEC];
  #pragma unroll
  for (int q = 0; q < VEC; ++q){
    float o = acc[q]*inv + bias[ch + q];
    if (apply_elu) o = (o > 0.f) ? o : (__expf(o) - 1.f);
    ov[q] = o;
  }
  if constexpr (VEC == 4) *(fvec4*)&out[(size_t)wid*HC + ch] = *(fvec4*)ov;
  else                    *(fvec2*)&out[(size_t)wid*HC + ch] = *(fvec2*)ov;
}

// ---------------- global mean pool ----------------
__global__ void k_pool(const float* __restrict__ h, const int* __restrict__ batch,
                       float* __restrict__ pool, int* __restrict__ gcnt, int N){
  int wid = (int)(((size_t)blockIdx.x * blockDim.x + threadIdx.x) >> 6);
  int lane = threadIdx.x & 63;
  if (wid >= N) return;
  int g = batch[wid];
  #pragma unroll
  for (int j = 0; j < 2; ++j)
    atomicAdd(&pool[(size_t)g*128 + j*64 + lane], h[(size_t)wid*128 + j*64 + lane]);
  if (lane == 0) atomicAdd(&gcnt[g], 1);
}

__global__ void k_pool_div(const float* __restrict__ pool, const int* __restrict__ gcnt,
                           float* __restrict__ out, int total){
  int i = blockIdx.x*blockDim.x + threadIdx.x;
  if (i < total) out[i] = pool[i] / fmaxf((float)gcnt[i >> 7], 1.f);
}

extern "C" void kernel_launch(void* const* d_in, const int* in_sizes, int n_in,
                              void* d_out, int out_size, void* d_ws, size_t ws_size,
                              hipStream_t stream){
  const float* x    = (const float*)d_in[0];
  const int*   ei   = (const int*)  d_in[1];
  const int*   batch= (const int*)  d_in[2];
  const float* Wl1  = (const float*)d_in[3];
  const float* bl1  = (const float*)d_in[4];
  const float* Wr1  = (const float*)d_in[5];
  const float* br1  = (const float*)d_in[6];
  const float* att1 = (const float*)d_in[7];
  const float* b1   = (const float*)d_in[8];
  const float* Wl2  = (const float*)d_in[9];
  const float* bl2  = (const float*)d_in[10];
  const float* Wr2  = (const float*)d_in[11];
  const float* br2  = (const float*)d_in[12];
  const float* att2 = (const float*)d_in[13];
  const float* b2   = (const float*)d_in[14];
  const float* Wl3  = (const float*)d_in[15];
  const float* bl3  = (const float*)d_in[16];
  const float* Wr3  = (const float*)d_in[17];
  const float* br3  = (const float*)d_in[18];
  const float* att3 = (const float*)d_in[19];
  const float* b3   = (const float*)d_in[20];

  int N  = in_sizes[2];          // 50000
  int E  = in_sizes[1] / 2;      // 800000
  int NG = out_size / 128;       // 1000
  const int* esrc = ei;
  const int* edst = ei + E;
  int Mpad = ((N + 127)/128)*128;

  size_t off = 0;
  char* base = (char*)d_ws;
  auto alloc = [&](size_t bytes)->void*{
    void* p = base + off;
    off += (bytes + 255) & ~(size_t)255;
    return p;
  };
  _Float16* XL = (_Float16*)alloc((size_t)Mpad*256*sizeof(_Float16));
  _Float16* XR = (_Float16*)alloc((size_t)Mpad*256*sizeof(_Float16));
  float*    Hb = (float*)   alloc((size_t)Mpad*256*sizeof(float));
  _Float16* WT = (_Float16*)alloc((size_t)512*768*sizeof(_Float16));
  int* row_start = (int*)alloc(((size_t)N+1)*sizeof(int));
  int* edge_src  = (int*)alloc((size_t)(E+N)*sizeof(int));
  int* cnt       = (int*)alloc((size_t)N*sizeof(int));
  int* bsum      = (int*)alloc(256*sizeof(int));
  float* pool    = (float*)alloc((size_t)NG*128*sizeof(float));
  int* gcnt      = (int*)alloc((size_t)NG*sizeof(int));
  (void)ws_size; (void)n_in;

  int EN = E + N;
  int nb = (N + 255) / 256;

  // CSR build
  hipMemsetAsync(cnt, 0, (size_t)N*sizeof(int), stream);
  k_count<<<(EN+255)/256, 256, 0, stream>>>(edst, E, N, cnt);
  k_scan_block<<<nb, 256, 0, stream>>>(cnt, row_start, bsum, N);
  k_scan_tops<<<1, 256, 0, stream>>>(bsum, nb);
  k_scan_add<<<nb, 256, 0, stream>>>(row_start, bsum, N, EN);
  hipMemsetAsync(cnt, 0, (size_t)N*sizeof(int), stream);
  k_scatter<<<(EN+255)/256, 256, 0, stream>>>(esrc, edst, E, N, row_start, cnt, edge_src);

  dim3 blk(256);
  int agg_blocks = (N + 3) / 4;
  dim3 gemm_gA(Mpad/128, 4);     // 2*NwHalf = 512
  dim3 gemm_gB(Mpad/128, 2);     // 2*NwHalf = 256

  // ---- Layer 1: K=64 -> 4x64 ----
  k_splitW<<<(64*256+255)/256, blk, 0, stream>>>(Wl1, WT,           64, 256);
  k_splitW<<<(64*256+255)/256, blk, 0, stream>>>(Wr1, WT + 256*192, 64, 256);
  k_gemm_split<<<gemm_gA, blk, 0, stream>>>(x, WT, bl1, br1, XL, XR, N, 64, 256);
  k_gat_agg<256,64><<<agg_blocks, blk, 0, stream>>>(XL, XR, att1, b1, row_start, edge_src, Hb, N, 1);

  // ---- Layer 2: K=256 -> 4x64 ----
  k_splitW<<<(256*256+255)/256, blk, 0, stream>>>(Wl2, WT,           256, 256);
  k_splitW<<<(256*256+255)/256, blk, 0, stream>>>(Wr2, WT + 256*768, 256, 256);
  k_gemm_split<<<gemm_gA, blk, 0, stream>>>(Hb, WT, bl2, br2, XL, XR, N, 256, 256);
  k_gat_agg<256,64><<<agg_blocks, blk, 0, stream>>>(XL, XR, att2, b2, row_start, edge_src, Hb, N, 1);

  // ---- Layer 3: K=256 -> 128, 1 head, no concat, no elu ----
  k_splitW<<<(256*128+255)/256, blk, 0, stream>>>(Wl3, WT,           256, 128);
  k_splitW<<<(256*128+255)/256, blk, 0, stream>>>(Wr3, WT + 128*768, 256, 128);
  k_gemm_split<<<gemm_gB, blk, 0, stream>>>(Hb, WT, bl3, br3, XL, XR, N, 256, 128);
  k_gat_agg<128,128><<<agg_blocks, blk, 0, stream>>>(XL, XR, att3, b3, row_start, edge_src, Hb, N, 0);

  // ---- Global mean pool ----
  hipMemsetAsync(pool, 0, (size_t)NG*128*sizeof(float), stream);
  hipMemsetAsync(gcnt, 0, (size_t)NG*sizeof(int), stream);
  k_pool<<<agg_blocks, blk, 0, stream>>>(Hb, batch, pool, gcnt, N);
  k_pool_div<<<(NG*128+255)/256, 256, 0, stream>>>(pool, gcnt, (float*)d_out, NG*128);
}

// Round 5
// 559.312 us; speedup vs baseline: 4.0341x; 1.2475x over previous
//
#include <hip/hip_runtime.h>
#include <math.h>

#define NEG_SLOPE 0.2f

typedef _Float16 half8 __attribute__((ext_vector_type(8)));
typedef _Float16 half4 __attribute__((ext_vector_type(4)));
typedef _Float16 half2v __attribute__((ext_vector_type(2)));
typedef float    f32x4 __attribute__((ext_vector_type(4)));
typedef float    fvec4 __attribute__((ext_vector_type(4)));
typedef float    fvec2 __attribute__((ext_vector_type(2)));

// ---------------- CSR build ----------------
__global__ void k_count(const int* __restrict__ dst, int E, int N, int* __restrict__ cnt){
  int i = blockIdx.x*blockDim.x + threadIdx.x;
  if (i < E) atomicAdd(&cnt[dst[i]], 1);
  else if (i < E + N) atomicAdd(&cnt[i - E], 1);   // self loops
}

__global__ void k_scan_block(const int* __restrict__ cnt, int* __restrict__ ex,
                             int* __restrict__ bsum, int N){
  __shared__ int tmp[256];
  int t = threadIdx.x;
  int i = blockIdx.x*256 + t;
  int v = (i < N) ? cnt[i] : 0;
  tmp[t] = v; __syncthreads();
  for (int off = 1; off < 256; off <<= 1){
    int u = (t >= off) ? tmp[t-off] : 0;
    __syncthreads();
    tmp[t] += u;
    __syncthreads();
  }
  if (i < N) ex[i] = tmp[t] - v;
  if (t == 255) bsum[blockIdx.x] = tmp[255];
}

__global__ void k_scan_tops(int* __restrict__ bsum, int nb){
  __shared__ int tmp[256];
  int t = threadIdx.x;
  int v = (t < nb) ? bsum[t] : 0;
  tmp[t] = v; __syncthreads();
  for (int off = 1; off < 256; off <<= 1){
    int u = (t >= off) ? tmp[t-off] : 0;
    __syncthreads();
    tmp[t] += u;
    __syncthreads();
  }
  if (t < nb) bsum[t] = tmp[t] - v;
}

__global__ void k_scan_add(int* __restrict__ row_start, const int* __restrict__ bsum,
                           int N, int total){
  int i = blockIdx.x*256 + threadIdx.x;
  if (i < N) row_start[i] += bsum[blockIdx.x];
  if (i == 0) row_start[N] = total;
}

__global__ void k_scatter(const int* __restrict__ src, const int* __restrict__ dst,
                          int E, int N, const int* __restrict__ row_start,
                          int* __restrict__ cursor, int* __restrict__ edge_src){
  int i = blockIdx.x*blockDim.x + threadIdx.x;
  if (i < E){
    int d = dst[i];
    int p = atomicAdd(&cursor[d], 1);
    edge_src[row_start[d] + p] = src[i];
  } else if (i < E + N){
    int n = i - E;
    int p = atomicAdd(&cursor[n], 1);
    edge_src[row_start[n] + p] = n;
  }
}

// ---------------- W split: W[K][Nw] fp32 -> WT[Nw][2K] f16 rows [Wh(K)|Wl(K)] ----------------
__global__ void k_splitW(const float* __restrict__ W, _Float16* __restrict__ WT,
                         int K, int Nw){
  int id = blockIdx.x*blockDim.x + threadIdx.x;
  if (id >= K*Nw) return;
  int n = id / K, k = id % K;
  float w = W[(size_t)k*Nw + n];
  _Float16 h = (_Float16)w;
  _Float16 l = (_Float16)(w - (float)h);
  size_t base = (size_t)n*2*K;
  WT[base + k]     = h;
  WT[base + K + k] = l;
}

// ---------------- x split: x[N][K] fp32 -> X16[N][2K] f16 rows [xh(K)|xl(K)] ----------------
__global__ void k_split_x(const float* __restrict__ x, _Float16* __restrict__ X16,
                          int N, int K){
  int id = blockIdx.x*blockDim.x + threadIdx.x;
  int per = K/8;
  if (id >= N*per) return;
  int rr = id / per, c = (id % per)*8;
  fvec4 f0 = *(const fvec4*)&x[(size_t)rr*K + c];
  fvec4 f1 = *(const fvec4*)&x[(size_t)rr*K + c + 4];
  half8 hh, hl;
  #pragma unroll
  for (int q = 0; q < 4; ++q){
    _Float16 h0 = (_Float16)f0[q];
    hh[q] = h0; hl[q] = (_Float16)(f0[q] - (float)h0);
    _Float16 h1 = (_Float16)f1[q];
    hh[4+q] = h1; hl[4+q] = (_Float16)(f1[q] - (float)h1);
  }
  *(half8*)&X16[(size_t)rr*2*K + c]     = hh;
  *(half8*)&X16[(size_t)rr*2*K + K + c] = hl;
}

// ---------------- split-f16 MFMA GEMM, chunk-interleaved, merged L/R ----------------
// [XL|XR] = A @ [Wl|Wr] + bias, A16 rows = [Ah(K)|Al(K)], WT rows = [Wh(K)|Wl(K)].
// Per 64-chunk: stage Ah,Al,Wh,Wl tiles; acc += Ah*Wh + Al*Wh + Ah*Wl.
// 1D grid, bijective XCD swizzle: same-x column-blocks land on one XCD (y fastest).
__global__ __launch_bounds__(256, 2)
void k_gemm_split(const _Float16* __restrict__ A16, const _Float16* __restrict__ WT,
                  const float* __restrict__ biasL, const float* __restrict__ biasR,
                  _Float16* __restrict__ XL, _Float16* __restrict__ XR,
                  int M, int K, int NwHalf, int gy, int qq, int rr){
  __shared__ _Float16 sAh[128*72];
  __shared__ _Float16 sAl[128*72];
  __shared__ _Float16 sWh[128*72];
  __shared__ _Float16 sWl[128*72];
  const int tid  = threadIdx.x;
  const int lane = tid & 63;
  const int wid  = tid >> 6;
  const int wm   = wid >> 1, wn = wid & 1;

  // bijective xcd-chunked remap: hw id -> logical l, consecutive l share one XCD
  const int h   = blockIdx.x;
  const int xcd = h & 7, idx = h >> 3;
  const int l   = xcd*qq + (xcd < rr ? xcd : rr) + idx;
  const int bx  = l / gy, by = l - bx*gy;
  const int m0  = bx * 128;
  const int n0  = by * 128;
  const int lda = 2*K;

  f32x4 acc[4][4];
  #pragma unroll
  for (int i = 0; i < 4; ++i)
    #pragma unroll
    for (int j = 0; j < 4; ++j)
      acc[i][j] = (f32x4){0.f,0.f,0.f,0.f};

  const int l15 = lane & 15;
  const int lhi = lane >> 4;

  const int nc = K/64;
  for (int c = 0; c < nc; ++c){
    const int kA = c*64;
    #pragma unroll
    for (int it = 0; it < 4; ++it){
      int idx2 = it*256 + tid;          // 0..1023
      int r = idx2 >> 3, c8 = idx2 & 7;
      int gr = m0 + r;
      half8 vh = (half8)(_Float16)0.f, vl = (half8)(_Float16)0.f;
      if (gr < M){
        vh = *(const half8*)&A16[(size_t)gr*lda + kA + c8*8];
        vl = *(const half8*)&A16[(size_t)gr*lda + K + kA + c8*8];
      }
      *(half8*)&sAh[r*72 + c8*8] = vh;
      *(half8*)&sAl[r*72 + c8*8] = vl;
      int wr = n0 + r;
      *(half8*)&sWh[r*72 + c8*8] = *(const half8*)&WT[(size_t)wr*lda + kA + c8*8];
      *(half8*)&sWl[r*72 + c8*8] = *(const half8*)&WT[(size_t)wr*lda + K + kA + c8*8];
    }
    __syncthreads();
    #pragma unroll
    for (int ks = 0; ks < 64; ks += 32){
      half8 ah[4], al[4], bh[4], bl[4];
      #pragma unroll
      for (int fm = 0; fm < 4; ++fm){
        ah[fm] = *(const half8*)&sAh[(wm*64 + fm*16 + l15)*72 + ks + 8*lhi];
        al[fm] = *(const half8*)&sAl[(wm*64 + fm*16 + l15)*72 + ks + 8*lhi];
      }
      #pragma unroll
      for (int fn = 0; fn < 4; ++fn){
        bh[fn] = *(const half8*)&sWh[(wn*64 + fn*16 + l15)*72 + ks + 8*lhi];
        bl[fn] = *(const half8*)&sWl[(wn*64 + fn*16 + l15)*72 + ks + 8*lhi];
      }
      #pragma unroll
      for (int fm = 0; fm < 4; ++fm)
        #pragma unroll
        for (int fn = 0; fn < 4; ++fn)
          acc[fm][fn] = __builtin_amdgcn_mfma_f32_16x16x32_f16(ah[fm], bh[fn], acc[fm][fn], 0, 0, 0);
      #pragma unroll
      for (int fm = 0; fm < 4; ++fm)
        #pragma unroll
        for (int fn = 0; fn < 4; ++fn)
          acc[fm][fn] = __builtin_amdgcn_mfma_f32_16x16x32_f16(al[fm], bh[fn], acc[fm][fn], 0, 0, 0);
      #pragma unroll
      for (int fm = 0; fm < 4; ++fm)
        #pragma unroll
        for (int fn = 0; fn < 4; ++fn)
          acc[fm][fn] = __builtin_amdgcn_mfma_f32_16x16x32_f16(ah[fm], bl[fn], acc[fm][fn], 0, 0, 0);
    }
    __syncthreads();
  }
  // epilogue: block-uniform L/R select, f16 store
  const bool isR = (n0 >= NwHalf);
  const float* bias = isR ? biasR : biasL;
  _Float16* Xo = isR ? XR : XL;
  const int nbase = isR ? (n0 - NwHalf) : n0;
  #pragma unroll
  for (int fm = 0; fm < 4; ++fm){
    #pragma unroll
    for (int fn = 0; fn < 4; ++fn){
      int cc = nbase + wn*64 + fn*16 + l15;
      float bv = bias[cc];
      #pragma unroll
      for (int q = 0; q < 4; ++q){
        int row = m0 + wm*64 + fm*16 + lhi*4 + q;
        if (row < M) Xo[(size_t)row*NwHalf + cc] = (_Float16)(acc[fm][fn][q] + bv);
      }
    }
  }
}

// ---------------- GATv2 aggregation: f16 gather, head-local reduce ----------------
// SPLIT=1: out rows are [Hh(HC)|Hl(HC)] f16 (feeds next GEMM); SPLIT=0: fp32 out.
template<int HC, int C, int SPLIT>
__global__ __launch_bounds__(256) void k_gat_agg(const _Float16* __restrict__ xl,
                                                 const _Float16* __restrict__ xr,
                                                 const float* __restrict__ att,
                                                 const float* __restrict__ bias,
                                                 const int* __restrict__ row_start,
                                                 const int* __restrict__ edge_src,
                                                 void* __restrict__ outp,
                                                 int N, int apply_elu){
  constexpr int VEC   = HC/64;     // floats per lane
  constexpr int GROUP = C/VEC;     // lanes per head
  int wid = (int)(((size_t)blockIdx.x * blockDim.x + threadIdx.x) >> 6);
  int lane = threadIdx.x & 63;
  if (wid >= N) return;

  const int ch = (lane/GROUP)*C + (lane%GROUP)*VEC;   // my channel base

  float attv[VEC], xrrv[VEC], acc[VEC];
  #pragma unroll
  for (int q = 0; q < VEC; ++q) attv[q] = att[ch + q];
  {
    if constexpr (VEC == 4){
      half4 hv = *(const half4*)&xr[(size_t)wid*HC + ch];
      #pragma unroll
      for (int q = 0; q < 4; ++q) xrrv[q] = (float)hv[q];
    } else {
      half2v hv = *(const half2v*)&xr[(size_t)wid*HC + ch];
      #pragma unroll
      for (int q = 0; q < 2; ++q) xrrv[q] = (float)hv[q];
    }
  }
  #pragma unroll
  for (int q = 0; q < VEC; ++q) acc[q] = 0.f;
  float m = -INFINITY, s = 0.f;

  const int e0 = row_start[wid], e1 = row_start[wid+1];

  auto loadrow = [&](int sn, float* dstv){
    if constexpr (VEC == 4){
      half4 hv = *(const half4*)&xl[(size_t)sn*HC + ch];
      #pragma unroll
      for (int q = 0; q < 4; ++q) dstv[q] = (float)hv[q];
    } else {
      half2v hv = *(const half2v*)&xl[(size_t)sn*HC + ch];
      #pragma unroll
      for (int q = 0; q < 2; ++q) dstv[q] = (float)hv[q];
    }
  };
  auto edge_logit = [&](const float* xv)->float{
    float tv = 0.f;
    #pragma unroll
    for (int q = 0; q < VEC; ++q){
      float v = xv[q] + xrrv[q];
      v = (v > 0.f) ? v : NEG_SLOPE*v;
      tv = fmaf(v, attv[q], tv);
    }
    #pragma unroll
    for (int off = GROUP/2; off > 0; off >>= 1)
      tv += __shfl_xor(tv, off, 64);
    return tv;
  };

  int e = e0;
  for (; e + 1 < e1; e += 2){
    int sa = edge_src[e], sb = edge_src[e+1];
    float xa[VEC], xb[VEC];
    loadrow(sa, xa);
    loadrow(sb, xb);
    float ta = edge_logit(xa);
    float tb = edge_logit(xb);
    float nm = fmaxf(fmaxf(m, ta), tb);
    float wo = __expf(m - nm);
    float pa = __expf(ta - nm);
    float pb = __expf(tb - nm);
    s = s*wo + pa + pb;
    m = nm;
    #pragma unroll
    for (int q = 0; q < VEC; ++q)
      acc[q] = fmaf(pa, xa[q], fmaf(pb, xb[q], acc[q]*wo));
  }
  if (e < e1){
    int sa = edge_src[e];
    float xa[VEC];
    loadrow(sa, xa);
    float ta = edge_logit(xa);
    float nm = fmaxf(m, ta);
    float wo = __expf(m - nm);
    float pa = __expf(ta - nm);
    s = s*wo + pa;
    m = nm;
    #pragma unroll
    for (int q = 0; q < VEC; ++q)
      acc[q] = fmaf(pa, xa[q], acc[q]*wo);
  }

  float inv = 1.f / s;
  float ov[VEC];
  #pragma unroll
  for (int q = 0; q < VEC; ++q){
    float o = acc[q]*inv + bias[ch + q];
    if (apply_elu) o = (o > 0.f) ? o : (__expf(o) - 1.f);
    ov[q] = o;
  }
  if constexpr (SPLIT){
    _Float16* o16 = (_Float16*)outp;
    _Float16 hh[VEC], hl[VEC];
    #pragma unroll
    for (int q = 0; q < VEC; ++q){
      _Float16 hv = (_Float16)ov[q];
      hh[q] = hv; hl[q] = (_Float16)(ov[q] - (float)hv);
    }
    if constexpr (VEC == 4){
      *(half4*)&o16[(size_t)wid*2*HC + ch]      = *(half4*)hh;
      *(half4*)&o16[(size_t)wid*2*HC + HC + ch] = *(half4*)hl;
    } else {
      *(half2v*)&o16[(size_t)wid*2*HC + ch]      = *(half2v*)hh;
      *(half2v*)&o16[(size_t)wid*2*HC + HC + ch] = *(half2v*)hl;
    }
  } else {
    float* o32 = (float*)outp;
    if constexpr (VEC == 4) *(fvec4*)&o32[(size_t)wid*HC + ch] = *(fvec4*)ov;
    else                    *(fvec2*)&o32[(size_t)wid*HC + ch] = *(fvec2*)ov;
  }
}

// ---------------- global mean pool ----------------
__global__ void k_pool(const float* __restrict__ h, const int* __restrict__ batch,
                       float* __restrict__ pool, int* __restrict__ gcnt, int N){
  int wid = (int)(((size_t)blockIdx.x * blockDim.x + threadIdx.x) >> 6);
  int lane = threadIdx.x & 63;
  if (wid >= N) return;
  int g = batch[wid];
  #pragma unroll
  for (int j = 0; j < 2; ++j)
    atomicAdd(&pool[(size_t)g*128 + j*64 + lane], h[(size_t)wid*128 + j*64 + lane]);
  if (lane == 0) atomicAdd(&gcnt[g], 1);
}

__global__ void k_pool_div(const float* __restrict__ pool, const int* __restrict__ gcnt,
                           float* __restrict__ out, int total){
  int i = blockIdx.x*blockDim.x + threadIdx.x;
  if (i < total) out[i] = pool[i] / fmaxf((float)gcnt[i >> 7], 1.f);
}

extern "C" void kernel_launch(void* const* d_in, const int* in_sizes, int n_in,
                              void* d_out, int out_size, void* d_ws, size_t ws_size,
                              hipStream_t stream){
  const float* x    = (const float*)d_in[0];
  const int*   ei   = (const int*)  d_in[1];
  const int*   batch= (const int*)  d_in[2];
  const float* Wl1  = (const float*)d_in[3];
  const float* bl1  = (const float*)d_in[4];
  const float* Wr1  = (const float*)d_in[5];
  const float* br1  = (const float*)d_in[6];
  const float* att1 = (const float*)d_in[7];
  const float* b1   = (const float*)d_in[8];
  const float* Wl2  = (const float*)d_in[9];
  const float* bl2  = (const float*)d_in[10];
  const float* Wr2  = (const float*)d_in[11];
  const float* br2  = (const float*)d_in[12];
  const float* att2 = (const float*)d_in[13];
  const float* b2   = (const float*)d_in[14];
  const float* Wl3  = (const float*)d_in[15];
  const float* bl3  = (const float*)d_in[16];
  const float* Wr3  = (const float*)d_in[17];
  const float* br3  = (const float*)d_in[18];
  const float* att3 = (const float*)d_in[19];
  const float* b3   = (const float*)d_in[20];

  int N  = in_sizes[2];          // 50000
  int E  = in_sizes[1] / 2;      // 800000
  int NG = out_size / 128;       // 1000
  const int* esrc = ei;
  const int* edst = ei + E;
  int Mpad = ((N + 127)/128)*128;

  size_t off = 0;
  char* base = (char*)d_ws;
  auto alloc = [&](size_t bytes)->void*{
    void* p = base + off;
    off += (bytes + 255) & ~(size_t)255;
    return p;
  };
  _Float16* XL  = (_Float16*)alloc((size_t)Mpad*256*sizeof(_Float16));
  _Float16* XR  = (_Float16*)alloc((size_t)Mpad*256*sizeof(_Float16));
  _Float16* Hsp = (_Float16*)alloc((size_t)Mpad*512*sizeof(_Float16)); // [Hh|Hl]
  _Float16* X16 = (_Float16*)alloc((size_t)Mpad*128*sizeof(_Float16)); // [xh|xl]
  float*    Hb32= (float*)   alloc((size_t)Mpad*128*sizeof(float));    // layer-3 out
  _Float16* WT  = (_Float16*)alloc((size_t)512*512*sizeof(_Float16));
  int* row_start = (int*)alloc(((size_t)N+1)*sizeof(int));
  int* edge_src  = (int*)alloc((size_t)(E+N)*sizeof(int));
  int* cnt       = (int*)alloc((size_t)N*sizeof(int));
  int* bsum      = (int*)alloc(256*sizeof(int));
  float* pool    = (float*)alloc((size_t)NG*128*sizeof(float));
  int* gcnt      = (int*)alloc((size_t)NG*sizeof(int));
  (void)ws_size; (void)n_in;

  int EN = E + N;
  int nb = (N + 255) / 256;

  // CSR build
  hipMemsetAsync(cnt, 0, (size_t)N*sizeof(int), stream);
  k_count<<<(EN+255)/256, 256, 0, stream>>>(edst, E, N, cnt);
  k_scan_block<<<nb, 256, 0, stream>>>(cnt, row_start, bsum, N);
  k_scan_tops<<<1, 256, 0, stream>>>(bsum, nb);
  k_scan_add<<<nb, 256, 0, stream>>>(row_start, bsum, N, EN);
  hipMemsetAsync(cnt, 0, (size_t)N*sizeof(int), stream);
  k_scatter<<<(EN+255)/256, 256, 0, stream>>>(esrc, edst, E, N, row_start, cnt, edge_src);

  dim3 blk(256);
  int agg_blocks = (N + 3) / 4;
  int gx = Mpad/128;             // 391
  int G1 = gx*4;                 // layers 1,2: 512 cols
  int G3 = gx*2;                 // layer 3: 256 cols

  // ---- Layer 1: K=64 -> 4x64 ----
  k_splitW<<<(64*256+255)/256, blk, 0, stream>>>(Wl1, WT,           64, 256);
  k_splitW<<<(64*256+255)/256, blk, 0, stream>>>(Wr1, WT + 256*128, 64, 256);
  k_split_x<<<((N*8)+255)/256, blk, 0, stream>>>(x, X16, N, 64);
  k_gemm_split<<<G1, blk, 0, stream>>>(X16, WT, bl1, br1, XL, XR, N, 64, 256, 4, G1/8, G1%8);
  k_gat_agg<256,64,1><<<agg_blocks, blk, 0, stream>>>(XL, XR, att1, b1, row_start, edge_src, Hsp, N, 1);

  // ---- Layer 2: K=256 -> 4x64 ----
  k_splitW<<<(256*256+255)/256, blk, 0, stream>>>(Wl2, WT,           256, 256);
  k_splitW<<<(256*256+255)/256, blk, 0, stream>>>(Wr2, WT + 256*512, 256, 256);
  k_gemm_split<<<G1, blk, 0, stream>>>(Hsp, WT, bl2, br2, XL, XR, N, 256, 256, 4, G1/8, G1%8);
  k_gat_agg<256,64,1><<<agg_blocks, blk, 0, stream>>>(XL, XR, att2, b2, row_start, edge_src, Hsp, N, 1);

  // ---- Layer 3: K=256 -> 128, 1 head, no concat, no elu ----
  k_splitW<<<(256*128+255)/256, blk, 0, stream>>>(Wl3, WT,           256, 128);
  k_splitW<<<(256*128+255)/256, blk, 0, stream>>>(Wr3, WT + 128*512, 256, 128);
  k_gemm_split<<<G3, blk, 0, stream>>>(Hsp, WT, bl3, br3, XL, XR, N, 256, 128, 2, G3/8, G3%8);
  k_gat_agg<128,128,0><<<agg_blocks, blk, 0, stream>>>(XL, XR, att3, b3, row_start, edge_src, Hb32, N, 0);

  // ---- Global mean pool ----
  hipMemsetAsync(pool, 0, (size_t)NG*128*sizeof(float), stream);
  hipMemsetAsync(gcnt, 0, (size_t)NG*sizeof(int), stream);
  k_pool<<<agg_blocks, blk, 0, stream>>>(Hb32, batch, pool, gcnt, N);
  k_pool_div<<<(NG*128+255)/256, 256, 0, stream>>>(pool, gcnt, (float*)d_out, NG*128);
}

// Round 6
// 522.992 us; speedup vs baseline: 4.3143x; 1.0694x over previous
//
#include <hip/hip_runtime.h>
#include <math.h>

#define NEG_SLOPE 0.2f

typedef _Float16 half8 __attribute__((ext_vector_type(8)));
typedef _Float16 half4 __attribute__((ext_vector_type(4)));
typedef _Float16 half2v __attribute__((ext_vector_type(2)));
typedef float    f32x4 __attribute__((ext_vector_type(4)));
typedef float    fvec4 __attribute__((ext_vector_type(4)));
typedef float    fvec2 __attribute__((ext_vector_type(2)));

// ---------------- CSR build ----------------
__global__ void k_count(const int* __restrict__ dst, int E, int N, int* __restrict__ cnt){
  int i = blockIdx.x*blockDim.x + threadIdx.x;
  if (i < E) atomicAdd(&cnt[dst[i]], 1);
  else if (i < E + N) atomicAdd(&cnt[i - E], 1);   // self loops
}

__global__ void k_scan_block(const int* __restrict__ cnt, int* __restrict__ ex,
                             int* __restrict__ bsum, int N){
  __shared__ int tmp[256];
  int t = threadIdx.x;
  int i = blockIdx.x*256 + t;
  int v = (i < N) ? cnt[i] : 0;
  tmp[t] = v; __syncthreads();
  for (int off = 1; off < 256; off <<= 1){
    int u = (t >= off) ? tmp[t-off] : 0;
    __syncthreads();
    tmp[t] += u;
    __syncthreads();
  }
  if (i < N) ex[i] = tmp[t] - v;
  if (t == 255) bsum[blockIdx.x] = tmp[255];
}

__global__ void k_scan_tops(int* __restrict__ bsum, int nb){
  __shared__ int tmp[256];
  int t = threadIdx.x;
  int v = (t < nb) ? bsum[t] : 0;
  tmp[t] = v; __syncthreads();
  for (int off = 1; off < 256; off <<= 1){
    int u = (t >= off) ? tmp[t-off] : 0;
    __syncthreads();
    tmp[t] += u;
    __syncthreads();
  }
  if (t < nb) bsum[t] = tmp[t] - v;
}

__global__ void k_scan_add(int* __restrict__ row_start, const int* __restrict__ bsum,
                           int N, int total){
  int i = blockIdx.x*256 + threadIdx.x;
  if (i < N) row_start[i] += bsum[blockIdx.x];
  if (i == 0) row_start[N] = total;
}

__global__ void k_scatter(const int* __restrict__ src, const int* __restrict__ dst,
                          int E, int N, const int* __restrict__ row_start,
                          int* __restrict__ cursor, int* __restrict__ edge_src){
  int i = blockIdx.x*blockDim.x + threadIdx.x;
  if (i < E){
    int d = dst[i];
    int p = atomicAdd(&cursor[d], 1);
    edge_src[row_start[d] + p] = src[i];
  } else if (i < E + N){
    int n = i - E;
    int p = atomicAdd(&cursor[n], 1);
    edge_src[row_start[n] + p] = n;
  }
}

// ---------------- W split: W[K][Nw] fp32 -> WT[Nw][2K] f16 rows [Wh(K)|Wl(K)] ----------------
__global__ void k_splitW(const float* __restrict__ W, _Float16* __restrict__ WT,
                         int K, int Nw){
  int id = blockIdx.x*blockDim.x + threadIdx.x;
  if (id >= K*Nw) return;
  int n = id / K, k = id % K;
  float w = W[(size_t)k*Nw + n];
  _Float16 h = (_Float16)w;
  _Float16 l = (_Float16)(w - (float)h);
  size_t base = (size_t)n*2*K;
  WT[base + k]     = h;
  WT[base + K + k] = l;
}

// ---------------- x split: x[N][K] fp32 -> X16[N][2K] f16 rows [xh(K)|xl(K)] ----------------
__global__ void k_split_x(const float* __restrict__ x, _Float16* __restrict__ X16,
                          int N, int K){
  int id = blockIdx.x*blockDim.x + threadIdx.x;
  int per = K/8;
  if (id >= N*per) return;
  int rr = id / per, c = (id % per)*8;
  fvec4 f0 = *(const fvec4*)&x[(size_t)rr*K + c];
  fvec4 f1 = *(const fvec4*)&x[(size_t)rr*K + c + 4];
  half8 hh, hl;
  #pragma unroll
  for (int q = 0; q < 4; ++q){
    _Float16 h0 = (_Float16)f0[q];
    hh[q] = h0; hl[q] = (_Float16)(f0[q] - (float)h0);
    _Float16 h1 = (_Float16)f1[q];
    hh[4+q] = h1; hl[4+q] = (_Float16)(f1[q] - (float)h1);
  }
  *(half8*)&X16[(size_t)rr*2*K + c]     = hh;
  *(half8*)&X16[(size_t)rr*2*K + K + c] = hl;
}

// ---------------- split-f16 MFMA GEMM, chunk-interleaved, merged L/R ----------------
__global__ __launch_bounds__(256, 2)
void k_gemm_split(const _Float16* __restrict__ A16, const _Float16* __restrict__ WT,
                  const float* __restrict__ biasL, const float* __restrict__ biasR,
                  _Float16* __restrict__ XL, _Float16* __restrict__ XR,
                  int M, int K, int NwHalf, int gy, int qq, int rr){
  __shared__ _Float16 sAh[128*72];
  __shared__ _Float16 sAl[128*72];
  __shared__ _Float16 sWh[128*72];
  __shared__ _Float16 sWl[128*72];
  const int tid  = threadIdx.x;
  const int lane = tid & 63;
  const int wid  = tid >> 6;
  const int wm   = wid >> 1, wn = wid & 1;

  const int h   = blockIdx.x;
  const int xcd = h & 7, idx = h >> 3;
  const int l   = xcd*qq + (xcd < rr ? xcd : rr) + idx;
  const int bx  = l / gy, by = l - bx*gy;
  const int m0  = bx * 128;
  const int n0  = by * 128;
  const int lda = 2*K;

  f32x4 acc[4][4];
  #pragma unroll
  for (int i = 0; i < 4; ++i)
    #pragma unroll
    for (int j = 0; j < 4; ++j)
      acc[i][j] = (f32x4){0.f,0.f,0.f,0.f};

  const int l15 = lane & 15;
  const int lhi = lane >> 4;

  const int nc = K/64;
  for (int c = 0; c < nc; ++c){
    const int kA = c*64;
    #pragma unroll
    for (int it = 0; it < 4; ++it){
      int idx2 = it*256 + tid;
      int r = idx2 >> 3, c8 = idx2 & 7;
      int gr = m0 + r;
      half8 vh = (half8)(_Float16)0.f, vl = (half8)(_Float16)0.f;
      if (gr < M){
        vh = *(const half8*)&A16[(size_t)gr*lda + kA + c8*8];
        vl = *(const half8*)&A16[(size_t)gr*lda + K + kA + c8*8];
      }
      *(half8*)&sAh[r*72 + c8*8] = vh;
      *(half8*)&sAl[r*72 + c8*8] = vl;
      int wr = n0 + r;
      *(half8*)&sWh[r*72 + c8*8] = *(const half8*)&WT[(size_t)wr*lda + kA + c8*8];
      *(half8*)&sWl[r*72 + c8*8] = *(const half8*)&WT[(size_t)wr*lda + K + kA + c8*8];
    }
    __syncthreads();
    #pragma unroll
    for (int ks = 0; ks < 64; ks += 32){
      half8 ah[4], al[4], bh[4], bl[4];
      #pragma unroll
      for (int fm = 0; fm < 4; ++fm){
        ah[fm] = *(const half8*)&sAh[(wm*64 + fm*16 + l15)*72 + ks + 8*lhi];
        al[fm] = *(const half8*)&sAl[(wm*64 + fm*16 + l15)*72 + ks + 8*lhi];
      }
      #pragma unroll
      for (int fn = 0; fn < 4; ++fn){
        bh[fn] = *(const half8*)&sWh[(wn*64 + fn*16 + l15)*72 + ks + 8*lhi];
        bl[fn] = *(const half8*)&sWl[(wn*64 + fn*16 + l15)*72 + ks + 8*lhi];
      }
      #pragma unroll
      for (int fm = 0; fm < 4; ++fm)
        #pragma unroll
        for (int fn = 0; fn < 4; ++fn)
          acc[fm][fn] = __builtin_amdgcn_mfma_f32_16x16x32_f16(ah[fm], bh[fn], acc[fm][fn], 0, 0, 0);
      #pragma unroll
      for (int fm = 0; fm < 4; ++fm)
        #pragma unroll
        for (int fn = 0; fn < 4; ++fn)
          acc[fm][fn] = __builtin_amdgcn_mfma_f32_16x16x32_f16(al[fm], bh[fn], acc[fm][fn], 0, 0, 0);
      #pragma unroll
      for (int fm = 0; fm < 4; ++fm)
        #pragma unroll
        for (int fn = 0; fn < 4; ++fn)
          acc[fm][fn] = __builtin_amdgcn_mfma_f32_16x16x32_f16(ah[fm], bl[fn], acc[fm][fn], 0, 0, 0);
    }
    __syncthreads();
  }
  const bool isR = (n0 >= NwHalf);
  const float* bias = isR ? biasR : biasL;
  _Float16* Xo = isR ? XR : XL;
  const int nbase = isR ? (n0 - NwHalf) : n0;
  #pragma unroll
  for (int fm = 0; fm < 4; ++fm){
    #pragma unroll
    for (int fn = 0; fn < 4; ++fn){
      int cc = nbase + wn*64 + fn*16 + l15;
      float bv = bias[cc];
      #pragma unroll
      for (int q = 0; q < 4; ++q){
        int row = m0 + wm*64 + fm*16 + lhi*4 + q;
        if (row < M) Xo[(size_t)row*NwHalf + cc] = (_Float16)(acc[fm][fn][q] + bv);
      }
    }
  }
}

// ---------------- GATv2 aggregation v3: packed-f16 + dot2, 4-edge unroll ----------------
// SPLIT=1: out rows are [Hh(HC)|Hl(HC)] f16 (feeds next GEMM); SPLIT=0: fp32 out.
template<int HC, int C, int SPLIT>
__global__ __launch_bounds__(256) void k_gat_agg(const _Float16* __restrict__ xl,
                                                 const _Float16* __restrict__ xr,
                                                 const float* __restrict__ att,
                                                 const float* __restrict__ bias,
                                                 const int* __restrict__ row_start,
                                                 const int* __restrict__ edge_src,
                                                 void* __restrict__ outp,
                                                 int N, int apply_elu){
  constexpr int VEC   = HC/64;     // channels per lane (4 or 2)
  constexpr int NP    = VEC/2;     // half2 pairs per lane
  constexpr int GROUP = C/VEC;     // lanes per head
  int wid = (int)(((size_t)blockIdx.x * blockDim.x + threadIdx.x) >> 6);
  int lane = threadIdx.x & 63;
  if (wid >= N) return;

  const int ch = (lane/GROUP)*C + (lane%GROUP)*VEC;   // my channel base

  const half2v hz = {(_Float16)0.f, (_Float16)0.f};
  half2v attv2[NP], xrr2[NP];
  #pragma unroll
  for (int p = 0; p < NP; ++p){
    half2v a; a[0] = (_Float16)att[ch + 2*p]; a[1] = (_Float16)att[ch + 2*p + 1];
    attv2[p] = a;
  }
  {
    if constexpr (VEC == 4){
      half4 hv = *(const half4*)&xr[(size_t)wid*HC + ch];
      xrr2[0][0] = hv[0]; xrr2[0][1] = hv[1];
      xrr2[1][0] = hv[2]; xrr2[1][1] = hv[3];
    } else {
      xrr2[0] = *(const half2v*)&xr[(size_t)wid*HC + ch];
    }
  }
  float acc[VEC];
  #pragma unroll
  for (int q = 0; q < VEC; ++q) acc[q] = 0.f;
  float m = -INFINITY, s = 0.f;

  const int e0 = row_start[wid], e1 = row_start[wid+1];
  const _Float16* xlb = xl + ch;

  auto loadrow = [&](int sn, half2v* d){
    if constexpr (VEC == 4){
      half4 hv = *(const half4*)(xlb + (size_t)sn*HC);
      d[0][0] = hv[0]; d[0][1] = hv[1];
      d[1][0] = hv[2]; d[1][1] = hv[3];
    } else {
      d[0] = *(const half2v*)(xlb + (size_t)sn*HC);
    }
  };
  // logit: pk_add, pk_max, pk_min, 2x v_dot2_f32_f16; slope applied in f32
  auto edge_logit = [&](const half2v* xv)->float{
    float tp = 0.f, tn = 0.f;
    #pragma unroll
    for (int p = 0; p < NP; ++p){
      half2v v   = xv[p] + xrr2[p];
      half2v pos = __builtin_elementwise_max(v, hz);
      half2v neg = __builtin_elementwise_min(v, hz);
      tp = __builtin_amdgcn_fdot2(pos, attv2[p], tp, false);
      tn = __builtin_amdgcn_fdot2(neg, attv2[p], tn, false);
    }
    float tv = fmaf(NEG_SLOPE, tn, tp);
    #pragma unroll
    for (int off = GROUP/2; off > 0; off >>= 1)
      tv += __shfl_xor(tv, off, 64);
    return tv;
  };
  auto getf = [&](const half2v* a, int q)->float{
    return (float)a[q>>1][q&1];     // q compile-time under unroll -> fma_mix
  };

  int e = e0;
  for (; e + 3 < e1; e += 4){
    int s0 = edge_src[e], s1 = edge_src[e+1], s2 = edge_src[e+2], s3 = edge_src[e+3];
    half2v x0[NP], x1[NP], x2[NP], x3[NP];
    loadrow(s0, x0); loadrow(s1, x1); loadrow(s2, x2); loadrow(s3, x3);
    float t0 = edge_logit(x0);
    float t1 = edge_logit(x1);
    float t2 = edge_logit(x2);
    float t3 = edge_logit(x3);
    float nm = fmaxf(fmaxf(m, t0), fmaxf(fmaxf(t1, t2), t3));
    float wo = __expf(m - nm);
    float p0 = __expf(t0 - nm), p1 = __expf(t1 - nm);
    float p2 = __expf(t2 - nm), p3 = __expf(t3 - nm);
    s = s*wo + (p0 + p1) + (p2 + p3);
    m = nm;
    #pragma unroll
    for (int q = 0; q < VEC; ++q){
      float a = acc[q]*wo;
      a = fmaf(p0, getf(x0,q), a);
      a = fmaf(p1, getf(x1,q), a);
      a = fmaf(p2, getf(x2,q), a);
      a = fmaf(p3, getf(x3,q), a);
      acc[q] = a;
    }
  }
  for (; e < e1; ++e){
    int sa = edge_src[e];
    half2v xa[NP];
    loadrow(sa, xa);
    float ta = edge_logit(xa);
    float nm = fmaxf(m, ta);
    float wo = __expf(m - nm);
    float pa = __expf(ta - nm);
    s = s*wo + pa;
    m = nm;
    #pragma unroll
    for (int q = 0; q < VEC; ++q)
      acc[q] = fmaf(pa, getf(xa,q), acc[q]*wo);
  }

  float inv = 1.f / s;
  float ov[VEC];
  #pragma unroll
  for (int q = 0; q < VEC; ++q){
    float o = acc[q]*inv + bias[ch + q];
    if (apply_elu) o = (o > 0.f) ? o : (__expf(o) - 1.f);
    ov[q] = o;
  }
  if constexpr (SPLIT){
    _Float16* o16 = (_Float16*)outp;
    _Float16 hh[VEC], hl[VEC];
    #pragma unroll
    for (int q = 0; q < VEC; ++q){
      _Float16 hv = (_Float16)ov[q];
      hh[q] = hv; hl[q] = (_Float16)(ov[q] - (float)hv);
    }
    if constexpr (VEC == 4){
      *(half4*)&o16[(size_t)wid*2*HC + ch]      = *(half4*)hh;
      *(half4*)&o16[(size_t)wid*2*HC + HC + ch] = *(half4*)hl;
    } else {
      *(half2v*)&o16[(size_t)wid*2*HC + ch]      = *(half2v*)hh;
      *(half2v*)&o16[(size_t)wid*2*HC + HC + ch] = *(half2v*)hl;
    }
  } else {
    float* o32 = (float*)outp;
    if constexpr (VEC == 4) *(fvec4*)&o32[(size_t)wid*HC + ch] = *(fvec4*)ov;
    else                    *(fvec2*)&o32[(size_t)wid*HC + ch] = *(fvec2*)ov;
  }
}

// ---------------- global mean pool ----------------
__global__ void k_pool(const float* __restrict__ h, const int* __restrict__ batch,
                       float* __restrict__ pool, int* __restrict__ gcnt, int N){
  int wid = (int)(((size_t)blockIdx.x * blockDim.x + threadIdx.x) >> 6);
  int lane = threadIdx.x & 63;
  if (wid >= N) return;
  int g = batch[wid];
  #pragma unroll
  for (int j = 0; j < 2; ++j)
    atomicAdd(&pool[(size_t)g*128 + j*64 + lane], h[(size_t)wid*128 + j*64 + lane]);
  if (lane == 0) atomicAdd(&gcnt[g], 1);
}

__global__ void k_pool_div(const float* __restrict__ pool, const int* __restrict__ gcnt,
                           float* __restrict__ out, int total){
  int i = blockIdx.x*blockDim.x + threadIdx.x;
  if (i < total) out[i] = pool[i] / fmaxf((float)gcnt[i >> 7], 1.f);
}

extern "C" void kernel_launch(void* const* d_in, const int* in_sizes, int n_in,
                              void* d_out, int out_size, void* d_ws, size_t ws_size,
                              hipStream_t stream){
  const float* x    = (const float*)d_in[0];
  const int*   ei   = (const int*)  d_in[1];
  const int*   batch= (const int*)  d_in[2];
  const float* Wl1  = (const float*)d_in[3];
  const float* bl1  = (const float*)d_in[4];
  const float* Wr1  = (const float*)d_in[5];
  const float* br1  = (const float*)d_in[6];
  const float* att1 = (const float*)d_in[7];
  const float* b1   = (const float*)d_in[8];
  const float* Wl2  = (const float*)d_in[9];
  const float* bl2  = (const float*)d_in[10];
  const float* Wr2  = (const float*)d_in[11];
  const float* br2  = (const float*)d_in[12];
  const float* att2 = (const float*)d_in[13];
  const float* b2   = (const float*)d_in[14];
  const float* Wl3  = (const float*)d_in[15];
  const float* bl3  = (const float*)d_in[16];
  const float* Wr3  = (const float*)d_in[17];
  const float* br3  = (const float*)d_in[18];
  const float* att3 = (const float*)d_in[19];
  const float* b3   = (const float*)d_in[20];

  int N  = in_sizes[2];          // 50000
  int E  = in_sizes[1] / 2;      // 800000
  int NG = out_size / 128;       // 1000
  const int* esrc = ei;
  const int* edst = ei + E;
  int Mpad = ((N + 127)/128)*128;

  size_t off = 0;
  char* base = (char*)d_ws;
  auto alloc = [&](size_t bytes)->void*{
    void* p = base + off;
    off += (bytes + 255) & ~(size_t)255;
    return p;
  };
  _Float16* XL  = (_Float16*)alloc((size_t)Mpad*256*sizeof(_Float16));
  _Float16* XR  = (_Float16*)alloc((size_t)Mpad*256*sizeof(_Float16));
  _Float16* Hsp = (_Float16*)alloc((size_t)Mpad*512*sizeof(_Float16)); // [Hh|Hl]
  _Float16* X16 = (_Float16*)alloc((size_t)Mpad*128*sizeof(_Float16)); // [xh|xl]
  float*    Hb32= (float*)   alloc((size_t)Mpad*128*sizeof(float));    // layer-3 out
  _Float16* WT  = (_Float16*)alloc((size_t)512*512*sizeof(_Float16));
  int* row_start = (int*)alloc(((size_t)N+1)*sizeof(int));
  int* edge_src  = (int*)alloc((size_t)(E+N)*sizeof(int));
  int* cnt       = (int*)alloc((size_t)N*sizeof(int));
  int* bsum      = (int*)alloc(256*sizeof(int));
  float* pool    = (float*)alloc((size_t)NG*128*sizeof(float));
  int* gcnt      = (int*)alloc((size_t)NG*sizeof(int));
  (void)ws_size; (void)n_in;

  int EN = E + N;
  int nb = (N + 255) / 256;

  // CSR build
  hipMemsetAsync(cnt, 0, (size_t)N*sizeof(int), stream);
  k_count<<<(EN+255)/256, 256, 0, stream>>>(edst, E, N, cnt);
  k_scan_block<<<nb, 256, 0, stream>>>(cnt, row_start, bsum, N);
  k_scan_tops<<<1, 256, 0, stream>>>(bsum, nb);
  k_scan_add<<<nb, 256, 0, stream>>>(row_start, bsum, N, EN);
  hipMemsetAsync(cnt, 0, (size_t)N*sizeof(int), stream);
  k_scatter<<<(EN+255)/256, 256, 0, stream>>>(esrc, edst, E, N, row_start, cnt, edge_src);

  dim3 blk(256);
  int agg_blocks = (N + 3) / 4;
  int gx = Mpad/128;             // 391
  int G1 = gx*4;                 // layers 1,2: 512 cols
  int G3 = gx*2;                 // layer 3: 256 cols

  // ---- Layer 1: K=64 -> 4x64 ----
  k_splitW<<<(64*256+255)/256, blk, 0, stream>>>(Wl1, WT,           64, 256);
  k_splitW<<<(64*256+255)/256, blk, 0, stream>>>(Wr1, WT + 256*128, 64, 256);
  k_split_x<<<((N*8)+255)/256, blk, 0, stream>>>(x, X16, N, 64);
  k_gemm_split<<<G1, blk, 0, stream>>>(X16, WT, bl1, br1, XL, XR, N, 64, 256, 4, G1/8, G1%8);
  k_gat_agg<256,64,1><<<agg_blocks, blk, 0, stream>>>(XL, XR, att1, b1, row_start, edge_src, Hsp, N, 1);

  // ---- Layer 2: K=256 -> 4x64 ----
  k_splitW<<<(256*256+255)/256, blk, 0, stream>>>(Wl2, WT,           256, 256);
  k_splitW<<<(256*256+255)/256, blk, 0, stream>>>(Wr2, WT + 256*512, 256, 256);
  k_gemm_split<<<G1, blk, 0, stream>>>(Hsp, WT, bl2, br2, XL, XR, N, 256, 256, 4, G1/8, G1%8);
  k_gat_agg<256,64,1><<<agg_blocks, blk, 0, stream>>>(XL, XR, att2, b2, row_start, edge_src, Hsp, N, 1);

  // ---- Layer 3: K=256 -> 128, 1 head, no concat, no elu ----
  k_splitW<<<(256*128+255)/256, blk, 0, stream>>>(Wl3, WT,           256, 128);
  k_splitW<<<(256*128+255)/256, blk, 0, stream>>>(Wr3, WT + 128*512, 256, 128);
  k_gemm_split<<<G3, blk, 0, stream>>>(Hsp, WT, bl3, br3, XL, XR, N, 256, 128, 2, G3/8, G3%8);
  k_gat_agg<128,128,0><<<agg_blocks, blk, 0, stream>>>(XL, XR, att3, b3, row_start, edge_src, Hb32, N, 0);

  // ---- Global mean pool ----
  hipMemsetAsync(pool, 0, (size_t)NG*128*sizeof(float), stream);
  hipMemsetAsync(gcnt, 0, (size_t)NG*sizeof(int), stream);
  k_pool<<<agg_blocks, blk, 0, stream>>>(Hb32, batch, pool, gcnt, N);
  k_pool_div<<<(NG*128+255)/256, 256, 0, stream>>>(pool, gcnt, (float*)d_out, NG*128);
}

// Round 7
// 500.854 us; speedup vs baseline: 4.5050x; 1.0442x over previous
//
#include <hip/hip_runtime.h>
#include <math.h>

#define NEG_SLOPE 0.2f

typedef _Float16 half8 __attribute__((ext_vector_type(8)));
typedef _Float16 half4 __attribute__((ext_vector_type(4)));
typedef _Float16 half2v __attribute__((ext_vector_type(2)));
typedef float    f32x4 __attribute__((ext_vector_type(4)));
typedef float    fvec4 __attribute__((ext_vector_type(4)));
typedef float    fvec2 __attribute__((ext_vector_type(2)));

// ---------------- CSR build ----------------
__global__ void k_count(const int* __restrict__ dst, int E, int N, int* __restrict__ cnt){
  int i = blockIdx.x*blockDim.x + threadIdx.x;
  if (i < E) atomicAdd(&cnt[dst[i]], 1);
  else if (i < E + N) atomicAdd(&cnt[i - E], 1);   // self loops
}

__global__ void k_scan_block(const int* __restrict__ cnt, int* __restrict__ ex,
                             int* __restrict__ bsum, int N){
  __shared__ int tmp[256];
  int t = threadIdx.x;
  int i = blockIdx.x*256 + t;
  int v = (i < N) ? cnt[i] : 0;
  tmp[t] = v; __syncthreads();
  for (int off = 1; off < 256; off <<= 1){
    int u = (t >= off) ? tmp[t-off] : 0;
    __syncthreads();
    tmp[t] += u;
    __syncthreads();
  }
  if (i < N) ex[i] = tmp[t] - v;
  if (t == 255) bsum[blockIdx.x] = tmp[255];
}

__global__ void k_scan_tops(int* __restrict__ bsum, int nb){
  __shared__ int tmp[256];
  int t = threadIdx.x;
  int v = (t < nb) ? bsum[t] : 0;
  tmp[t] = v; __syncthreads();
  for (int off = 1; off < 256; off <<= 1){
    int u = (t >= off) ? tmp[t-off] : 0;
    __syncthreads();
    tmp[t] += u;
    __syncthreads();
  }
  if (t < nb) bsum[t] = tmp[t] - v;
}

__global__ void k_scan_add(int* __restrict__ row_start, const int* __restrict__ bsum,
                           int N, int total){
  int i = blockIdx.x*256 + threadIdx.x;
  if (i < N) row_start[i] += bsum[blockIdx.x];
  if (i == 0) row_start[N] = total;
}

__global__ void k_scatter(const int* __restrict__ src, const int* __restrict__ dst,
                          int E, int N, const int* __restrict__ row_start,
                          int* __restrict__ cursor, int* __restrict__ edge_src){
  int i = blockIdx.x*blockDim.x + threadIdx.x;
  if (i < E){
    int d = dst[i];
    int p = atomicAdd(&cursor[d], 1);
    edge_src[row_start[d] + p] = src[i];
  } else if (i < E + N){
    int n = i - E;
    int p = atomicAdd(&cursor[n], 1);
    edge_src[row_start[n] + p] = n;
  }
}

// ---------------- W split: W[K][Nw] fp32 -> WT[Nw][2K] f16 rows [Wh(K)|Wl(K)] ----------------
__global__ void k_splitW(const float* __restrict__ W, _Float16* __restrict__ WT,
                         int K, int Nw){
  int id = blockIdx.x*blockDim.x + threadIdx.x;
  if (id >= K*Nw) return;
  int n = id / K, k = id % K;
  float w = W[(size_t)k*Nw + n];
  _Float16 h = (_Float16)w;
  _Float16 l = (_Float16)(w - (float)h);
  size_t base = (size_t)n*2*K;
  WT[base + k]     = h;
  WT[base + K + k] = l;
}

// ---------------- x split: x[N][K] fp32 -> X16[N][2K] f16 rows [xh(K)|xl(K)] ----------------
__global__ void k_split_x(const float* __restrict__ x, _Float16* __restrict__ X16,
                          int N, int K){
  int id = blockIdx.x*blockDim.x + threadIdx.x;
  int per = K/8;
  if (id >= N*per) return;
  int rr = id / per, c = (id % per)*8;
  fvec4 f0 = *(const fvec4*)&x[(size_t)rr*K + c];
  fvec4 f1 = *(const fvec4*)&x[(size_t)rr*K + c + 4];
  half8 hh, hl;
  #pragma unroll
  for (int q = 0; q < 4; ++q){
    _Float16 h0 = (_Float16)f0[q];
    hh[q] = h0; hl[q] = (_Float16)(f0[q] - (float)h0);
    _Float16 h1 = (_Float16)f1[q];
    hh[4+q] = h1; hl[4+q] = (_Float16)(f1[q] - (float)h1);
  }
  *(half8*)&X16[(size_t)rr*2*K + c]     = hh;
  *(half8*)&X16[(size_t)rr*2*K + K + c] = hl;
}

// ---------------- split-f16 MFMA GEMM, chunk-interleaved, merged L/R ----------------
__global__ __launch_bounds__(256, 2)
void k_gemm_split(const _Float16* __restrict__ A16, const _Float16* __restrict__ WT,
                  const float* __restrict__ biasL, const float* __restrict__ biasR,
                  _Float16* __restrict__ XL, _Float16* __restrict__ XR,
                  int M, int K, int NwHalf, int gy, int qq, int rr){
  __shared__ _Float16 sAh[128*72];
  __shared__ _Float16 sAl[128*72];
  __shared__ _Float16 sWh[128*72];
  __shared__ _Float16 sWl[128*72];
  const int tid  = threadIdx.x;
  const int lane = tid & 63;
  const int wid  = tid >> 6;
  const int wm   = wid >> 1, wn = wid & 1;

  const int h   = blockIdx.x;
  const int xcd = h & 7, idx = h >> 3;
  const int l   = xcd*qq + (xcd < rr ? xcd : rr) + idx;
  const int bx  = l / gy, by = l - bx*gy;
  const int m0  = bx * 128;
  const int n0  = by * 128;
  const int lda = 2*K;

  f32x4 acc[4][4];
  #pragma unroll
  for (int i = 0; i < 4; ++i)
    #pragma unroll
    for (int j = 0; j < 4; ++j)
      acc[i][j] = (f32x4){0.f,0.f,0.f,0.f};

  const int l15 = lane & 15;
  const int lhi = lane >> 4;

  const int nc = K/64;
  for (int c = 0; c < nc; ++c){
    const int kA = c*64;
    #pragma unroll
    for (int it = 0; it < 4; ++it){
      int idx2 = it*256 + tid;
      int r = idx2 >> 3, c8 = idx2 & 7;
      int gr = m0 + r;
      half8 vh = (half8)(_Float16)0.f, vl = (half8)(_Float16)0.f;
      if (gr < M){
        vh = *(const half8*)&A16[(size_t)gr*lda + kA + c8*8];
        vl = *(const half8*)&A16[(size_t)gr*lda + K + kA + c8*8];
      }
      *(half8*)&sAh[r*72 + c8*8] = vh;
      *(half8*)&sAl[r*72 + c8*8] = vl;
      int wr = n0 + r;
      *(half8*)&sWh[r*72 + c8*8] = *(const half8*)&WT[(size_t)wr*lda + kA + c8*8];
      *(half8*)&sWl[r*72 + c8*8] = *(const half8*)&WT[(size_t)wr*lda + K + kA + c8*8];
    }
    __syncthreads();
    #pragma unroll
    for (int ks = 0; ks < 64; ks += 32){
      half8 ah[4], al[4], bh[4], bl[4];
      #pragma unroll
      for (int fm = 0; fm < 4; ++fm){
        ah[fm] = *(const half8*)&sAh[(wm*64 + fm*16 + l15)*72 + ks + 8*lhi];
        al[fm] = *(const half8*)&sAl[(wm*64 + fm*16 + l15)*72 + ks + 8*lhi];
      }
      #pragma unroll
      for (int fn = 0; fn < 4; ++fn){
        bh[fn] = *(const half8*)&sWh[(wn*64 + fn*16 + l15)*72 + ks + 8*lhi];
        bl[fn] = *(const half8*)&sWl[(wn*64 + fn*16 + l15)*72 + ks + 8*lhi];
      }
      #pragma unroll
      for (int fm = 0; fm < 4; ++fm)
        #pragma unroll
        for (int fn = 0; fn < 4; ++fn)
          acc[fm][fn] = __builtin_amdgcn_mfma_f32_16x16x32_f16(ah[fm], bh[fn], acc[fm][fn], 0, 0, 0);
      #pragma unroll
      for (int fm = 0; fm < 4; ++fm)
        #pragma unroll
        for (int fn = 0; fn < 4; ++fn)
          acc[fm][fn] = __builtin_amdgcn_mfma_f32_16x16x32_f16(al[fm], bh[fn], acc[fm][fn], 0, 0, 0);
      #pragma unroll
      for (int fm = 0; fm < 4; ++fm)
        #pragma unroll
        for (int fn = 0; fn < 4; ++fn)
          acc[fm][fn] = __builtin_amdgcn_mfma_f32_16x16x32_f16(ah[fm], bl[fn], acc[fm][fn], 0, 0, 0);
    }
    __syncthreads();
  }
  const bool isR = (n0 >= NwHalf);
  const float* bias = isR ? biasR : biasL;
  _Float16* Xo = isR ? XR : XL;
  const int nbase = isR ? (n0 - NwHalf) : n0;
  #pragma unroll
  for (int fm = 0; fm < 4; ++fm){
    #pragma unroll
    for (int fn = 0; fn < 4; ++fn){
      int cc = nbase + wn*64 + fn*16 + l15;
      float bv = bias[cc];
      #pragma unroll
      for (int q = 0; q < 4; ++q){
        int row = m0 + wm*64 + fm*16 + lhi*4 + q;
        if (row < M) Xo[(size_t)row*NwHalf + cc] = (_Float16)(acc[fm][fn][q] + bv);
      }
    }
  }
}

// ---------------- GATv2 aggregation v4: edge-slot split wave ----------------
// Lane owns VEC=8 consecutive channels (one half8 = 16B load). LPE = HC/8 lanes
// cover one edge; the wave processes EPW = 64/LPE edges concurrently (slots).
// Per-slot online softmax in exp2 domain (att pre-scaled by log2e), defer-max
// rescale, slot states merged once per node.
template<int HC, int C, int SPLIT>
__global__ __launch_bounds__(256) void k_gat_agg(const _Float16* __restrict__ xl,
                                                 const _Float16* __restrict__ xr,
                                                 const float* __restrict__ att,
                                                 const float* __restrict__ bias,
                                                 const int* __restrict__ row_start,
                                                 const int* __restrict__ edge_src,
                                                 void* __restrict__ outp,
                                                 int N, int apply_elu){
  constexpr int VEC   = 8;
  constexpr int LPE   = HC/VEC;    // lanes per edge (32 or 16)
  constexpr int EPW   = 64/LPE;    // edge slots per wave (2 or 4)
  constexpr int GROUP = C/VEC;     // lanes per head (8 or 16)
  const float M_INIT = -1.0e30f, T_INACT = -2.0e30f, THR = 11.54f; // ~8 nats

  int wid = (int)(((size_t)blockIdx.x * blockDim.x + threadIdx.x) >> 6);
  int lane = threadIdx.x & 63;
  if (wid >= N) return;
  const int h  = lane / LPE;                       // edge slot
  const int li = lane % LPE;
  const int ch = (li/GROUP)*C + (li%GROUP)*VEC;    // my channel base

  const _Float16 s16 = (_Float16)NEG_SLOPE;
  const half2v slope2 = {s16, s16};

  half2v attv2[4], xrr2[4];
  {
    fvec4 a0 = *(const fvec4*)&att[ch];
    fvec4 a1 = *(const fvec4*)&att[ch+4];
    const float L2E = 1.4426950408889634f;
    attv2[0][0]=(_Float16)(a0[0]*L2E); attv2[0][1]=(_Float16)(a0[1]*L2E);
    attv2[1][0]=(_Float16)(a0[2]*L2E); attv2[1][1]=(_Float16)(a0[3]*L2E);
    attv2[2][0]=(_Float16)(a1[0]*L2E); attv2[2][1]=(_Float16)(a1[1]*L2E);
    attv2[3][0]=(_Float16)(a1[2]*L2E); attv2[3][1]=(_Float16)(a1[3]*L2E);
    half8 hv = *(const half8*)&xr[(unsigned)(wid*HC) + ch];
    #pragma unroll
    for (int p = 0; p < 4; ++p){ xrr2[p][0] = hv[2*p]; xrr2[p][1] = hv[2*p+1]; }
  }

  float acc[VEC];
  #pragma unroll
  for (int q = 0; q < VEC; ++q) acc[q] = 0.f;
  float m = M_INIT, s = 0.f;

  const int e0   = row_start[wid];
  const int ecnt = row_start[wid+1] - e0;
  const _Float16* xlb = xl + ch;

  auto rowload = [&](int sn)->half8 {
    return *(const half8*)(xlb + (unsigned)(sn*HC));
  };
  auto logit1 = [&](half8 x8)->float{
    float t = 0.f;
    #pragma unroll
    for (int p = 0; p < 4; ++p){
      half2v xp; xp[0] = x8[2*p]; xp[1] = x8[2*p+1];
      half2v v  = xp + xrr2[p];
      half2v lv = __builtin_elementwise_max(v, v*slope2);   // leaky relu
      t = __builtin_amdgcn_fdot2(lv, attv2[p], t, false);
    }
    #pragma unroll
    for (int off = GROUP/2; off > 0; off >>= 1)
      t += __shfl_xor(t, off, 64);
    return t;
  };
  auto update2 = [&](float ta, float tb, half8 xa, half8 xb){
    float pm = fmaxf(ta, tb);
    if (__all(pm <= m + THR)){
      float pa = __builtin_amdgcn_exp2f(ta - m);
      float pb = __builtin_amdgcn_exp2f(tb - m);
      s += pa + pb;
      #pragma unroll
      for (int q = 0; q < VEC; ++q)
        acc[q] = fmaf(pa, (float)xa[q], fmaf(pb, (float)xb[q], acc[q]));
    } else {
      float nm = fmaxf(pm, m);
      float wo = __builtin_amdgcn_exp2f(m - nm);
      float pa = __builtin_amdgcn_exp2f(ta - nm);
      float pb = __builtin_amdgcn_exp2f(tb - nm);
      s = fmaf(s, wo, pa + pb);
      m = nm;
      #pragma unroll
      for (int q = 0; q < VEC; ++q)
        acc[q] = fmaf(pa, (float)xa[q], fmaf(pb, (float)xb[q], acc[q]*wo));
    }
  };

  int base = e0 + h;
  const int R = ecnt / (2*EPW);
  for (int r = 0; r < R; ++r, base += 2*EPW){
    int sa = edge_src[base];
    int sb = edge_src[base + EPW];
    half8 xa = rowload(sa);
    half8 xb = rowload(sb);
    float ta = logit1(xa);
    float tb = logit1(xb);
    update2(ta, tb, xa, xb);
  }
  if (2*EPW*R < ecnt){               // predicated tail pair (uniform branch)
    const int last = e0 + ecnt;
    bool a1 = base < last, a2 = base + EPW < last;
    int sa = a1 ? edge_src[base] : 0;
    int sb = a2 ? edge_src[base + EPW] : 0;
    half8 xa = rowload(sa);
    half8 xb = rowload(sb);
    float ta = logit1(xa); ta = a1 ? ta : T_INACT;
    float tb = logit1(xb); tb = a2 ? tb : T_INACT;
    update2(ta, tb, xa, xb);
  }

  // merge edge-slot states (lanes ±LPE hold same channels)
  #pragma unroll
  for (int off = LPE; off < 64; off <<= 1){
    float mo = __shfl_xor(m, off, 64);
    float so = __shfl_xor(s, off, 64);
    float M  = fmaxf(m, mo);
    float w  = __builtin_amdgcn_exp2f(m  - M);
    float wo = __builtin_amdgcn_exp2f(mo - M);
    s = s*w + so*wo;
    #pragma unroll
    for (int q = 0; q < VEC; ++q)
      acc[q] = acc[q]*w + __shfl_xor(acc[q], off, 64)*wo;
    m = M;
  }

  if (h == 0){
    float inv = 1.f / s;
    fvec4 b0 = *(const fvec4*)&bias[ch];
    fvec4 b1 = *(const fvec4*)&bias[ch+4];
    float ov[VEC];
    #pragma unroll
    for (int q = 0; q < VEC; ++q){
      float o = acc[q]*inv + (q < 4 ? b0[q] : b1[q-4]);
      if (apply_elu) o = (o > 0.f) ? o : (__expf(o) - 1.f);
      ov[q] = o;
    }
    if constexpr (SPLIT){
      _Float16* o16 = (_Float16*)outp;
      half8 hh, hl;
      #pragma unroll
      for (int q = 0; q < VEC; ++q){
        _Float16 hv = (_Float16)ov[q];
        hh[q] = hv; hl[q] = (_Float16)(ov[q] - (float)hv);
      }
      *(half8*)&o16[(unsigned)(wid*2*HC) + ch]      = hh;
      *(half8*)&o16[(unsigned)(wid*2*HC) + HC + ch] = hl;
    } else {
      float* o32 = (float*)outp;
      *(fvec4*)&o32[(unsigned)(wid*HC) + ch]     = (fvec4){ov[0],ov[1],ov[2],ov[3]};
      *(fvec4*)&o32[(unsigned)(wid*HC) + ch + 4] = (fvec4){ov[4],ov[5],ov[6],ov[7]};
    }
  }
}

// ---------------- global mean pool ----------------
__global__ void k_pool(const float* __restrict__ h, const int* __restrict__ batch,
                       float* __restrict__ pool, int* __restrict__ gcnt, int N){
  int wid = (int)(((size_t)blockIdx.x * blockDim.x + threadIdx.x) >> 6);
  int lane = threadIdx.x & 63;
  if (wid >= N) return;
  int g = batch[wid];
  #pragma unroll
  for (int j = 0; j < 2; ++j)
    atomicAdd(&pool[(size_t)g*128 + j*64 + lane], h[(size_t)wid*128 + j*64 + lane]);
  if (lane == 0) atomicAdd(&gcnt[g], 1);
}

__global__ void k_pool_div(const float* __restrict__ pool, const int* __restrict__ gcnt,
                           float* __restrict__ out, int total){
  int i = blockIdx.x*blockDim.x + threadIdx.x;
  if (i < total) out[i] = pool[i] / fmaxf((float)gcnt[i >> 7], 1.f);
}

extern "C" void kernel_launch(void* const* d_in, const int* in_sizes, int n_in,
                              void* d_out, int out_size, void* d_ws, size_t ws_size,
                              hipStream_t stream){
  const float* x    = (const float*)d_in[0];
  const int*   ei   = (const int*)  d_in[1];
  const int*   batch= (const int*)  d_in[2];
  const float* Wl1  = (const float*)d_in[3];
  const float* bl1  = (const float*)d_in[4];
  const float* Wr1  = (const float*)d_in[5];
  const float* br1  = (const float*)d_in[6];
  const float* att1 = (const float*)d_in[7];
  const float* b1   = (const float*)d_in[8];
  const float* Wl2  = (const float*)d_in[9];
  const float* bl2  = (const float*)d_in[10];
  const float* Wr2  = (const float*)d_in[11];
  const float* br2  = (const float*)d_in[12];
  const float* att2 = (const float*)d_in[13];
  const float* b2   = (const float*)d_in[14];
  const float* Wl3  = (const float*)d_in[15];
  const float* bl3  = (const float*)d_in[16];
  const float* Wr3  = (const float*)d_in[17];
  const float* br3  = (const float*)d_in[18];
  const float* att3 = (const float*)d_in[19];
  const float* b3   = (const float*)d_in[20];

  int N  = in_sizes[2];          // 50000
  int E  = in_sizes[1] / 2;      // 800000
  int NG = out_size / 128;       // 1000
  const int* esrc = ei;
  const int* edst = ei + E;
  int Mpad = ((N + 127)/128)*128;

  size_t off = 0;
  char* base = (char*)d_ws;
  auto alloc = [&](size_t bytes)->void*{
    void* p = base + off;
    off += (bytes + 255) & ~(size_t)255;
    return p;
  };
  _Float16* XL  = (_Float16*)alloc((size_t)Mpad*256*sizeof(_Float16));
  _Float16* XR  = (_Float16*)alloc((size_t)Mpad*256*sizeof(_Float16));
  _Float16* Hsp = (_Float16*)alloc((size_t)Mpad*512*sizeof(_Float16)); // [Hh|Hl]
  _Float16* X16 = (_Float16*)alloc((size_t)Mpad*128*sizeof(_Float16)); // [xh|xl]
  float*    Hb32= (float*)   alloc((size_t)Mpad*128*sizeof(float));    // layer-3 out
  _Float16* WT  = (_Float16*)alloc((size_t)512*512*sizeof(_Float16));
  int* row_start = (int*)alloc(((size_t)N+1)*sizeof(int));
  int* edge_src  = (int*)alloc((size_t)(E+N)*sizeof(int));
  int* cnt       = (int*)alloc((size_t)N*sizeof(int));
  int* bsum      = (int*)alloc(256*sizeof(int));
  float* pool    = (float*)alloc((size_t)NG*128*sizeof(float));
  int* gcnt      = (int*)alloc((size_t)NG*sizeof(int));
  (void)ws_size; (void)n_in;

  int EN = E + N;
  int nb = (N + 255) / 256;

  // CSR build
  hipMemsetAsync(cnt, 0, (size_t)N*sizeof(int), stream);
  k_count<<<(EN+255)/256, 256, 0, stream>>>(edst, E, N, cnt);
  k_scan_block<<<nb, 256, 0, stream>>>(cnt, row_start, bsum, N);
  k_scan_tops<<<1, 256, 0, stream>>>(bsum, nb);
  k_scan_add<<<nb, 256, 0, stream>>>(row_start, bsum, N, EN);
  hipMemsetAsync(cnt, 0, (size_t)N*sizeof(int), stream);
  k_scatter<<<(EN+255)/256, 256, 0, stream>>>(esrc, edst, E, N, row_start, cnt, edge_src);

  dim3 blk(256);
  int agg_blocks = (N + 3) / 4;
  int gx = Mpad/128;             // 391
  int G1 = gx*4;                 // layers 1,2: 512 cols
  int G3 = gx*2;                 // layer 3: 256 cols

  // ---- Layer 1: K=64 -> 4x64 ----
  k_splitW<<<(64*256+255)/256, blk, 0, stream>>>(Wl1, WT,           64, 256);
  k_splitW<<<(64*256+255)/256, blk, 0, stream>>>(Wr1, WT + 256*128, 64, 256);
  k_split_x<<<((N*8)+255)/256, blk, 0, stream>>>(x, X16, N, 64);
  k_gemm_split<<<G1, blk, 0, stream>>>(X16, WT, bl1, br1, XL, XR, N, 64, 256, 4, G1/8, G1%8);
  k_gat_agg<256,64,1><<<agg_blocks, blk, 0, stream>>>(XL, XR, att1, b1, row_start, edge_src, Hsp, N, 1);

  // ---- Layer 2: K=256 -> 4x64 ----
  k_splitW<<<(256*256+255)/256, blk, 0, stream>>>(Wl2, WT,           256, 256);
  k_splitW<<<(256*256+255)/256, blk, 0, stream>>>(Wr2, WT + 256*512, 256, 256);
  k_gemm_split<<<G1, blk, 0, stream>>>(Hsp, WT, bl2, br2, XL, XR, N, 256, 256, 4, G1/8, G1%8);
  k_gat_agg<256,64,1><<<agg_blocks, blk, 0, stream>>>(XL, XR, att2, b2, row_start, edge_src, Hsp, N, 1);

  // ---- Layer 3: K=256 -> 128, 1 head, no concat, no elu ----
  k_splitW<<<(256*128+255)/256, blk, 0, stream>>>(Wl3, WT,           256, 128);
  k_splitW<<<(256*128+255)/256, blk, 0, stream>>>(Wr3, WT + 128*512, 256, 128);
  k_gemm_split<<<G3, blk, 0, stream>>>(Hsp, WT, bl3, br3, XL, XR, N, 256, 128, 2, G3/8, G3%8);
  k_gat_agg<128,128,0><<<agg_blocks, blk, 0, stream>>>(XL, XR, att3, b3, row_start, edge_src, Hb32, N, 0);

  // ---- Global mean pool ----
  hipMemsetAsync(pool, 0, (size_t)NG*128*sizeof(float), stream);
  hipMemsetAsync(gcnt, 0, (size_t)NG*sizeof(int), stream);
  k_pool<<<agg_blocks, blk, 0, stream>>>(Hb32, batch, pool, gcnt, N);
  k_pool_div<<<(NG*128+255)/256, 256, 0, stream>>>(pool, gcnt, (float*)d_out, NG*128);
}